// Round 6
// baseline (653.233 us; speedup 1.0000x reference)
//
#include <hip/hip_runtime.h>
#include <math.h>

#define FF   256
#define HH   64
#define NHEADS 4
#define LLAY 3
#define GG   64
#define CCLS 10
#define SSHIFT 10           // src stripe = src >> 10  (1024 nodes = 1 MB fp16 KV)

typedef __attribute__((ext_vector_type(8))) short short8v;
typedef __attribute__((ext_vector_type(4))) float floatx4;
typedef __attribute__((ext_vector_type(2))) _Float16 h2v;

#if defined(__has_builtin)
#if __has_builtin(__builtin_amdgcn_fdot2)
#define HAS_FDOT2 1
#endif
#endif

__device__ __forceinline__ unsigned short f2bf(float f) {
    unsigned int u = __float_as_uint(f);
    unsigned int r = (u + 0x7fffu + ((u >> 16) & 1u)) >> 16;   // RNE
    return (unsigned short)r;
}
__device__ __forceinline__ float bf2f(unsigned short h) {
    return __uint_as_float((unsigned int)h << 16);
}
__device__ __forceinline__ unsigned short f2h(float f) {
    _Float16 h = (_Float16)f;
    return __builtin_bit_cast(unsigned short, h);
}
__device__ __forceinline__ float2 h2f(unsigned int u) {
    h2v h = __builtin_bit_cast(h2v, u);
    return make_float2((float)h.x, (float)h.y);
}
__device__ __forceinline__ float dot8h(uint4 k, uint4 q) {
#ifdef HAS_FDOT2
    float d = 0.f;
    d = __builtin_amdgcn_fdot2(__builtin_bit_cast(h2v, k.x), __builtin_bit_cast(h2v, q.x), d, false);
    d = __builtin_amdgcn_fdot2(__builtin_bit_cast(h2v, k.y), __builtin_bit_cast(h2v, q.y), d, false);
    d = __builtin_amdgcn_fdot2(__builtin_bit_cast(h2v, k.z), __builtin_bit_cast(h2v, q.z), d, false);
    d = __builtin_amdgcn_fdot2(__builtin_bit_cast(h2v, k.w), __builtin_bit_cast(h2v, q.w), d, false);
    return d;
#else
    float2 k0 = h2f(k.x), k1 = h2f(k.y), k2 = h2f(k.z), k3 = h2f(k.w);
    float2 q0 = h2f(q.x), q1 = h2f(q.y), q2 = h2f(q.z), q3 = h2f(q.w);
    return k0.x*q0.x + k0.y*q0.y + k1.x*q1.x + k1.y*q1.y +
           k2.x*q2.x + k2.y*q2.y + k3.x*q3.x + k3.y*q3.y;
#endif
}

// ---------------------------------------------------------------------------
// Weight packing (bf16 hi/lo panels for MFMA GEMMs)
// ---------------------------------------------------------------------------
__global__ void k_packw(const float* __restrict__ Wq, const float* __restrict__ Wk,
                        const float* __restrict__ Wv, const float* __restrict__ Ws,
                        unsigned short* __restrict__ panel) {
    int idx = blockIdx.x * 256 + threadIdx.x;          // over 3*832*64
    if (idx >= 3 * 832 * 64) return;
    int l = idx / (832 * 64);
    int rem = idx % (832 * 64);
    int c = rem / 64, k = rem % 64;
    float v;
    if (c < 256)      v = Wq[((size_t)l * 64 + k) * 256 + c];
    else if (c < 512) v = Wk[((size_t)l * 64 + k) * 256 + (c - 256)];
    else if (c < 768) v = Wv[((size_t)l * 64 + k) * 256 + (c - 512)];
    else              v = Ws[((size_t)l * 64 + k) * 64 + (c - 768)];
    unsigned short hi = f2bf(v);
    unsigned short lo = f2bf(v - bf2f(hi));
    panel[((size_t)l * 2 + 0) * 832 * 64 + rem] = hi;
    panel[((size_t)l * 2 + 1) * 832 * 64 + rem] = lo;
}

__global__ void k_packemb(const float* __restrict__ W, unsigned short* __restrict__ pE) {
    int idx = blockIdx.x * 256 + threadIdx.x;          // over 64*256
    if (idx >= 64 * 256) return;
    int c = idx / 256, k = idx % 256;
    float v = W[(size_t)k * 64 + c];
    unsigned short hi = f2bf(v);
    unsigned short lo = f2bf(v - bf2f(hi));
    pE[idx] = hi;
    pE[64 * 256 + idx] = lo;
}

// ---------------------------------------------------------------------------
// Stripe-bucketed CSR: key = dst*SN + (src>>SSHIFT). Edges of each node come
// out sorted by src stripe -> the attention sweep has L2 temporal locality.
// ---------------------------------------------------------------------------
__global__ void k_hist(const int* __restrict__ eiA, const int* __restrict__ eiB, int E,
                       int* __restrict__ counts0, int SN, size_t M) {
    int br = blockIdx.y;
    const int* ei = br ? eiB : eiA;
    int* c = counts0 + (size_t)br * M;
    int i = blockIdx.x * blockDim.x + threadIdx.x;
    if (i < E) {
        int src = ei[i], dst = ei[E + i];
        atomicAdd(&c[(size_t)dst * SN + (src >> SSHIFT)], 1);
    }
}

// two-level parallel exclusive scan over M = N*SN entries
__global__ void k_scan_part(const int* __restrict__ counts0, size_t M,
                            int* __restrict__ ip0, int* __restrict__ btot) {
    int br = blockIdx.y, b = blockIdx.x, t = threadIdx.x;
    const int* counts = counts0 + (size_t)br * M;
    int* ip = ip0 + (size_t)br * (M + 1);
    __shared__ int sd[1024];
    size_t i = (size_t)b * 1024 + t;
    int v = (i < M) ? counts[i] : 0;
    sd[t] = v;
    __syncthreads();
    for (int off = 1; off < 1024; off <<= 1) {
        int x = (t >= off) ? sd[t - off] : 0;
        __syncthreads();
        sd[t] += x;
        __syncthreads();
    }
    if (i < M) ip[i] = sd[t] - v;                  // local exclusive
    if (t == 1023) btot[br * 1024 + b] = sd[1023];
}

__global__ void k_scan_fix(size_t M, int nb, int* __restrict__ ip0,
                           int* __restrict__ cursor0, const int* __restrict__ btot) {
    int br = blockIdx.y, b = blockIdx.x, t = threadIdx.x;
    int* ip = ip0 + (size_t)br * (M + 1);
    int* cursor = cursor0 + (size_t)br * M;
    __shared__ int soff;
    if (t == 0) {
        int s = 0;
        for (int j = 0; j < b; ++j) s += btot[br * 1024 + j];
        soff = s;
        if (b == nb - 1) ip[M] = s + btot[br * 1024 + b];
    }
    __syncthreads();
    size_t i = (size_t)b * 1024 + t;
    if (i < M) {
        int val = ip[i] + soff;
        ip[i] = val;
        cursor[i] = val;
    }
}

__global__ void k_scatter(const int* __restrict__ eiA, const int* __restrict__ eiB, int E,
                          int* __restrict__ cursor0, int* __restrict__ srcs0,
                          int SN, size_t M) {
    int br = blockIdx.y;
    const int* ei = br ? eiB : eiA;
    int* cursor = cursor0 + (size_t)br * M;
    int* srcs = srcs0 + (size_t)br * E;
    int i = blockIdx.x * blockDim.x + threadIdx.x;
    if (i < E) {
        int src = ei[i], dst = ei[E + i];
        int p = atomicAdd(&cursor[(size_t)dst * SN + (src >> SSHIFT)], 1);
        srcs[p] = src;
    }
}

// ---------------------------------------------------------------------------
// Embedding MFMA: h[br] = x @ W_emb + b + temb[br].  M=32/block, both branches.
// ---------------------------------------------------------------------------
__global__ void k_embed(const float* __restrict__ xa, const float* __restrict__ xb,
                        const unsigned short* __restrict__ pE,
                        const float* __restrict__ bemb, const float* __restrict__ temb,
                        float* __restrict__ h0, int N) {
    int br = blockIdx.y;
    const float* x = br ? xb : xa;
    float* h = h0 + (size_t)br * N * HH;
    int t = threadIdx.x, lane = t & 63, wid = t >> 6;
    int arow = lane & 15, kg = lane >> 4;
    int mbase = blockIdx.x * 32;
    int n0 = min(mbase + arow, N - 1);
    int n1 = min(mbase + 16 + arow, N - 1);
    const float* x0 = x + (size_t)n0 * FF + kg * 8;
    const float* x1 = x + (size_t)n1 * FF + kg * 8;
    const unsigned short* bh = pE + (size_t)(wid * 16 + arow) * FF + kg * 8;
    const unsigned short* bl = bh + 64 * FF;
    floatx4 acc0 = {0.f, 0.f, 0.f, 0.f}, acc1 = {0.f, 0.f, 0.f, 0.f};
#pragma unroll
    for (int ks = 0; ks < 8; ++ks) {
        const float4* p0 = reinterpret_cast<const float4*>(x0 + ks * 32);
        float4 f00 = p0[0], f01 = p0[1];
        const float4* p1 = reinterpret_cast<const float4*>(x1 + ks * 32);
        float4 f10 = p1[0], f11 = p1[1];
        float v0[8] = {f00.x, f00.y, f00.z, f00.w, f01.x, f01.y, f01.z, f01.w};
        float v1[8] = {f10.x, f10.y, f10.z, f10.w, f11.x, f11.y, f11.z, f11.w};
        short8v a0h, a0l, a1h, a1l;
#pragma unroll
        for (int i = 0; i < 8; ++i) {
            unsigned short h0v = f2bf(v0[i]);
            a0h[i] = (short)h0v; a0l[i] = (short)f2bf(v0[i] - bf2f(h0v));
            unsigned short h1v = f2bf(v1[i]);
            a1h[i] = (short)h1v; a1l[i] = (short)f2bf(v1[i] - bf2f(h1v));
        }
        short8v bhv = *reinterpret_cast<const short8v*>(bh + ks * 32);
        short8v blv = *reinterpret_cast<const short8v*>(bl + ks * 32);
        acc0 = __builtin_amdgcn_mfma_f32_16x16x32_bf16(a0h, bhv, acc0, 0, 0, 0);
        acc0 = __builtin_amdgcn_mfma_f32_16x16x32_bf16(a0l, bhv, acc0, 0, 0, 0);
        acc0 = __builtin_amdgcn_mfma_f32_16x16x32_bf16(a0h, blv, acc0, 0, 0, 0);
        acc1 = __builtin_amdgcn_mfma_f32_16x16x32_bf16(a1h, bhv, acc1, 0, 0, 0);
        acc1 = __builtin_amdgcn_mfma_f32_16x16x32_bf16(a1l, bhv, acc1, 0, 0, 0);
        acc1 = __builtin_amdgcn_mfma_f32_16x16x32_bf16(a1h, blv, acc1, 0, 0, 0);
    }
    int col = wid * 16 + (lane & 15);
    float bias = bemb[col] + temb[(size_t)br * HH + col];
#pragma unroll
    for (int r = 0; r < 4; ++r) {
        int row0 = mbase + kg * 4 + r;
        if (row0 < N) h[(size_t)row0 * HH + col] = acc0[r] + bias;
        int row1 = mbase + 16 + kg * 4 + r;
        if (row1 < N) h[(size_t)row1 * HH + col] = acc1[r] + bias;
    }
}

// ---------------------------------------------------------------------------
// Projection MFMA: q/k/v (fp16) + skip (written back into h, f32).
// ---------------------------------------------------------------------------
__global__ void k_proj(float* __restrict__ h0, const unsigned short* __restrict__ panel,
                       const float* __restrict__ bq, const float* __restrict__ bk,
                       const float* __restrict__ bv, const float* __restrict__ bs,
                       unsigned short* __restrict__ q, unsigned short* __restrict__ kv,
                       int N, int br) {
    float* h = h0 + (size_t)br * N * HH;
    int t = threadIdx.x, lane = t & 63, wid = t >> 6;
    int arow = lane & 15, kg = lane >> 4;
    int mbase = blockIdx.x * 32;

    short8v Ah[2][2], Al[2][2];
#pragma unroll
    for (int mt = 0; mt < 2; ++mt) {
        int node = min(mbase + mt * 16 + arow, N - 1);
        const float* src = h + (size_t)node * HH + kg * 8;
#pragma unroll
        for (int ks = 0; ks < 2; ++ks) {
            const float4* pp = reinterpret_cast<const float4*>(src + ks * 32);
            float4 fa = pp[0], fb = pp[1];
            float v[8] = {fa.x, fa.y, fa.z, fa.w, fb.x, fb.y, fb.z, fb.w};
#pragma unroll
            for (int i = 0; i < 8; ++i) {
                unsigned short hi = f2bf(v[i]);
                Ah[mt][ks][i] = (short)hi;
                Al[mt][ks][i] = (short)f2bf(v[i] - bf2f(hi));
            }
        }
    }
    // all waves have consumed h before skip columns overwrite it below
    __syncthreads();

    const unsigned short* ph = panel;
    const unsigned short* pl = panel + 832 * 64;
#pragma unroll
    for (int j = 0; j < 13; ++j) {
        int nt = wid * 13 + j;
        size_t boff = (size_t)(nt * 16 + arow) * 64 + kg * 8;
        floatx4 acc0 = {0.f, 0.f, 0.f, 0.f}, acc1 = {0.f, 0.f, 0.f, 0.f};
#pragma unroll
        for (int ks = 0; ks < 2; ++ks) {
            short8v bh = *reinterpret_cast<const short8v*>(ph + boff + ks * 32);
            short8v bl = *reinterpret_cast<const short8v*>(pl + boff + ks * 32);
            acc0 = __builtin_amdgcn_mfma_f32_16x16x32_bf16(Ah[0][ks], bh, acc0, 0, 0, 0);
            acc0 = __builtin_amdgcn_mfma_f32_16x16x32_bf16(Al[0][ks], bh, acc0, 0, 0, 0);
            acc0 = __builtin_amdgcn_mfma_f32_16x16x32_bf16(Ah[0][ks], bl, acc0, 0, 0, 0);
            acc1 = __builtin_amdgcn_mfma_f32_16x16x32_bf16(Ah[1][ks], bh, acc1, 0, 0, 0);
            acc1 = __builtin_amdgcn_mfma_f32_16x16x32_bf16(Al[1][ks], bh, acc1, 0, 0, 0);
            acc1 = __builtin_amdgcn_mfma_f32_16x16x32_bf16(Ah[1][ks], bl, acc1, 0, 0, 0);
        }
        int col = nt * 16 + (lane & 15);
        float bias;
        if (col < 256) bias = bq[col];
        else if (col < 512) bias = bk[col - 256];
        else if (col < 768) bias = bv[col - 512];
        else bias = bs[col - 768];

        auto store_tile = [&](const floatx4& acc, int mrow0) {
#pragma unroll
            for (int r = 0; r < 4; ++r) {
                int node = mrow0 + kg * 4 + r;
                if (node < N) {
                    float val = acc[r] + bias;
                    if (col < 256)      q[(size_t)node * 256 + col] = f2h(val);
                    else if (col < 512) kv[(size_t)node * 512 + (col - 256)] = f2h(val);
                    else if (col < 768) kv[(size_t)node * 512 + 256 + (col - 512)] = f2h(val);
                    else                h[(size_t)node * HH + (col - 768)] = val;  // skip
                }
            }
        };
        store_tile(acc0, mbase);
        store_tile(acc1, mbase + 16);
    }
}

// ---------------------------------------------------------------------------
// Attention aggregate. One wave per node; 32 lanes per edge (2 edges/pass).
// Edges are src-stripe-sorted -> all waves sweep the same ~1-3 MB KV window
// at the same time -> L2-resident gathers.
// ---------------------------------------------------------------------------
__global__ void k_attn(const unsigned short* __restrict__ qb,
                       const unsigned short* __restrict__ kvb,
                       const int* __restrict__ ip0, const int* __restrict__ srcs0,
                       float* __restrict__ h0, int N, int E, int br, int SN, size_t M) {
    const int* ip2 = ip0 + (size_t)br * (M + 1);
    const int* srcs = srcs0 + (size_t)br * E;
    float* h = h0 + (size_t)br * N * HH;

    int t = threadIdx.x;
    int lane = t & 63;
    int half = lane >> 5;
    int il = lane & 31;
    int o = il & 7;
    int elemoff = (il >> 3) * 64 + o * 8;

    int wvg = blockIdx.x * 4 + (t >> 6);
    int nw = gridDim.x * 4;
    for (int n = wvg; n < N; n += nw) {
        int beg = ip2[(size_t)n * SN], end = ip2[(size_t)n * SN + SN];
        if (end == beg) {
            if (lane < 8) {
                float4 s0 = *reinterpret_cast<const float4*>(&h[(size_t)n * HH + o * 8]);
                float4 s1 = *reinterpret_cast<const float4*>(&h[(size_t)n * HH + o * 8 + 4]);
                s0.x = fmaxf(s0.x, 0.f); s0.y = fmaxf(s0.y, 0.f);
                s0.z = fmaxf(s0.z, 0.f); s0.w = fmaxf(s0.w, 0.f);
                s1.x = fmaxf(s1.x, 0.f); s1.y = fmaxf(s1.y, 0.f);
                s1.z = fmaxf(s1.z, 0.f); s1.w = fmaxf(s1.w, 0.f);
                *reinterpret_cast<float4*>(&h[(size_t)n * HH + o * 8]) = s0;
                *reinterpret_cast<float4*>(&h[(size_t)n * HH + o * 8 + 4]) = s1;
            }
            continue;
        }
        uint4 q4 = *reinterpret_cast<const uint4*>(qb + (size_t)n * 256 + elemoff);
        float m = -INFINITY, s = 0.f;
        float a0=0.f,a1=0.f,a2=0.f,a3=0.f,a4=0.f,a5=0.f,a6=0.f,a7=0.f;

        for (int e0 = beg; e0 < end; e0 += 8) {
            uint4 kk[4], vv[4];
            bool vd[4];
#pragma unroll
            for (int i = 0; i < 4; ++i) {
                int ei = e0 + 2 * i + half;
                bool ok = ei < end;
                vd[i] = ok;
                int src = srcs[ok ? ei : beg];
                const unsigned short* kb = kvb + ((size_t)src << 9) + elemoff;
                kk[i] = *reinterpret_cast<const uint4*>(kb);
                vv[i] = *reinterpret_cast<const uint4*>(kb + 256);
            }
            float lg[4];
#pragma unroll
            for (int i = 0; i < 4; ++i) {
                float d = dot8h(kk[i], q4);
                d += __shfl_xor(d, 1);
                d += __shfl_xor(d, 2);
                d += __shfl_xor(d, 4);
                lg[i] = vd[i] ? d * 0.125f : -INFINITY;
            }
            float cm = fmaxf(fmaxf(lg[0], lg[1]), fmaxf(lg[2], lg[3]));
            float mn = fmaxf(m, cm);
            float rs = (m == -INFINITY) ? 0.f : __expf(m - mn);
            s *= rs;
            a0*=rs; a1*=rs; a2*=rs; a3*=rs; a4*=rs; a5*=rs; a6*=rs; a7*=rs;
            m = mn;
#pragma unroll
            for (int i = 0; i < 4; ++i) {
                float p = vd[i] ? __expf(lg[i] - mn) : 0.f;
                s += p;
                float2 v01 = h2f(vv[i].x), v23 = h2f(vv[i].y);
                float2 v45 = h2f(vv[i].z), v67 = h2f(vv[i].w);
                a0 += p * v01.x; a1 += p * v01.y; a2 += p * v23.x; a3 += p * v23.y;
                a4 += p * v45.x; a5 += p * v45.y; a6 += p * v67.x; a7 += p * v67.y;
            }
        }
        // merge the two halves (independent online softmaxes)
        float mo = __shfl_xor(m, 32);
        float mt2 = fmaxf(m, mo);
        float myscale = (m == -INFINITY) ? 0.f : __expf(m - mt2);
        float ss = s * myscale;
        float st = ss + __shfl_xor(ss, 32);
        float inv = 1.f / st;
        a0 *= myscale; a0 += __shfl_xor(a0, 32);
        a1 *= myscale; a1 += __shfl_xor(a1, 32);
        a2 *= myscale; a2 += __shfl_xor(a2, 32);
        a3 *= myscale; a3 += __shfl_xor(a3, 32);
        a4 *= myscale; a4 += __shfl_xor(a4, 32);
        a5 *= myscale; a5 += __shfl_xor(a5, 32);
        a6 *= myscale; a6 += __shfl_xor(a6, 32);
        a7 *= myscale; a7 += __shfl_xor(a7, 32);
        a0 *= inv; a1 *= inv; a2 *= inv; a3 *= inv;
        a4 *= inv; a5 *= inv; a6 *= inv; a7 *= inv;
        // head mean (sum over head bits 3,4 of il)
        a0 += __shfl_xor(a0, 8);  a0 += __shfl_xor(a0, 16);
        a1 += __shfl_xor(a1, 8);  a1 += __shfl_xor(a1, 16);
        a2 += __shfl_xor(a2, 8);  a2 += __shfl_xor(a2, 16);
        a3 += __shfl_xor(a3, 8);  a3 += __shfl_xor(a3, 16);
        a4 += __shfl_xor(a4, 8);  a4 += __shfl_xor(a4, 16);
        a5 += __shfl_xor(a5, 8);  a5 += __shfl_xor(a5, 16);
        a6 += __shfl_xor(a6, 8);  a6 += __shfl_xor(a6, 16);
        a7 += __shfl_xor(a7, 8);  a7 += __shfl_xor(a7, 16);
        if (lane < 8) {
            float4 s0 = *reinterpret_cast<const float4*>(&h[(size_t)n * HH + o * 8]);
            float4 s1 = *reinterpret_cast<const float4*>(&h[(size_t)n * HH + o * 8 + 4]);
            float4 r0, r1;
            r0.x = fmaxf(0.25f * a0 + s0.x, 0.f);
            r0.y = fmaxf(0.25f * a1 + s0.y, 0.f);
            r0.z = fmaxf(0.25f * a2 + s0.z, 0.f);
            r0.w = fmaxf(0.25f * a3 + s0.w, 0.f);
            r1.x = fmaxf(0.25f * a4 + s1.x, 0.f);
            r1.y = fmaxf(0.25f * a5 + s1.y, 0.f);
            r1.z = fmaxf(0.25f * a6 + s1.z, 0.f);
            r1.w = fmaxf(0.25f * a7 + s1.w, 0.f);
            *reinterpret_cast<float4*>(&h[(size_t)n * HH + o * 8]) = r0;
            *reinterpret_cast<float4*>(&h[(size_t)n * HH + o * 8 + 4]) = r1;
        }
    }
}

// ---------------------------------------------------------------------------
// Mean pool (batch sorted, run-length accumulate), both branches
// ---------------------------------------------------------------------------
__global__ void k_pool(const float* __restrict__ h0, const int* __restrict__ batA,
                       const int* __restrict__ batB,
                       float* __restrict__ pooled, float* __restrict__ cnt, int N) {
    int br = blockIdx.y;
    const float* h = h0 + (size_t)br * N * HH;
    const int* batch = br ? batB : batA;
    float* pb = pooled + (size_t)br * GG * HH;
    float* cb = cnt + (size_t)br * GG;
    int j = threadIdx.x;
    int n0 = blockIdx.x * 32;
    int n1 = min(n0 + 32, N);
    if (n0 >= N) return;
    float acc = 0.f;
    int c = 0;
    int gcur = batch[n0];
    for (int n = n0; n < n1; ++n) {
        int g = batch[n];
        if (g != gcur) {
            atomicAdd(&pb[gcur * HH + j], acc);
            if (j == 0) atomicAdd(&cb[gcur], (float)c);
            acc = 0.f; c = 0; gcur = g;
        }
        acc += h[(size_t)n * HH + j];
        ++c;
    }
    atomicAdd(&pb[gcur * HH + j], acc);
    if (j == 0) atomicAdd(&cb[gcur], (float)c);
}

// ---------------------------------------------------------------------------
// Head: mean-pool finalize, MHA over seq=2, mean, classifier. Block per graph.
// ---------------------------------------------------------------------------
__global__ void k_head(const float* __restrict__ pooled, const float* __restrict__ cnt,
                       const float* __restrict__ in_w, const float* __restrict__ in_b,
                       const float* __restrict__ out_w, const float* __restrict__ out_b,
                       const float* __restrict__ Wc1, const float* __restrict__ bc1,
                       const float* __restrict__ Wc2, const float* __restrict__ bc2,
                       float* __restrict__ out) {
    int g = blockIdx.x;
    int t = threadIdx.x;
    __shared__ float xs[2][HH];
    __shared__ float qkvs[2][3 * HH];
    __shared__ float sc[2][2][NHEADS];
    __shared__ float os[2][HH];
    __shared__ float xf[HH];
    __shared__ float r1[HH / 2];

    for (int s = 0; s < 2; ++s) {
        float c = fmaxf(cnt[s * GG + g], 1.f);
        xs[s][t] = pooled[(size_t)s * GG * HH + g * HH + t] / c;
    }
    __syncthreads();
    for (int idx = t; idx < 2 * 192; idx += 64) {
        int s = idx / 192, i = idx % 192;
        float a = in_b[i];
#pragma unroll 8
        for (int j = 0; j < HH; ++j) a += xs[s][j] * in_w[i * HH + j];
        qkvs[s][i] = a;
    }
    __syncthreads();
    if (t < 16) {
        int s1 = t >> 3, s2 = (t >> 2) & 1, hh = t & 3;
        float a = 0.f;
#pragma unroll
        for (int d = 0; d < 16; ++d) a += qkvs[s1][hh * 16 + d] * qkvs[s2][HH + hh * 16 + d];
        sc[s1][s2][hh] = a * 0.25f;
    }
    __syncthreads();
    {
        int hh = t >> 4;
        for (int s1 = 0; s1 < 2; ++s1) {
            float a0 = sc[s1][0][hh], a1 = sc[s1][1][hh];
            float mx = fmaxf(a0, a1);
            float e0 = __expf(a0 - mx), e1 = __expf(a1 - mx);
            float inv = 1.f / (e0 + e1);
            os[s1][t] = (e0 * inv) * qkvs[0][2 * HH + t] + (e1 * inv) * qkvs[1][2 * HH + t];
        }
    }
    __syncthreads();
    {
        float acc0 = 0.f, acc1 = 0.f;
#pragma unroll 8
        for (int k2 = 0; k2 < HH; ++k2) {
            float w = out_w[t * HH + k2];
            acc0 += os[0][k2] * w;
            acc1 += os[1][k2] * w;
        }
        xf[t] = 0.5f * (acc0 + acc1) + out_b[t];
    }
    __syncthreads();
    if (t < 32) {
        float a = bc1[t];
#pragma unroll 8
        for (int j = 0; j < HH; ++j) a += xf[j] * Wc1[j * 32 + t];
        r1[t] = fmaxf(a, 0.f);
    }
    __syncthreads();
    if (t < CCLS) {
        float a = bc2[t];
#pragma unroll
        for (int j2 = 0; j2 < 32; ++j2) a += r1[j2] * Wc2[j2 * CCLS + t];
        out[g * CCLS + t] = a;
    }
}

// ---------------------------------------------------------------------------
extern "C" void kernel_launch(void* const* d_in, const int* in_sizes, int n_in,
                              void* d_out, int out_size, void* d_ws, size_t ws_size,
                              hipStream_t stream) {
    const float* x1    = (const float*)d_in[0];
    const float* x2    = (const float*)d_in[1];
    const int*   ei1   = (const int*)d_in[2];
    const int*   ei2   = (const int*)d_in[3];
    const int*   bat1  = (const int*)d_in[4];
    const int*   bat2  = (const int*)d_in[5];
    const float* W_emb = (const float*)d_in[6];
    const float* b_emb = (const float*)d_in[7];
    const float* temb  = (const float*)d_in[8];
    const float* Wq    = (const float*)d_in[9];
    const float* bq    = (const float*)d_in[10];
    const float* Wk    = (const float*)d_in[11];
    const float* bk    = (const float*)d_in[12];
    const float* Wv    = (const float*)d_in[13];
    const float* bv    = (const float*)d_in[14];
    const float* Ws    = (const float*)d_in[15];
    const float* bs    = (const float*)d_in[16];
    const float* miw   = (const float*)d_in[17];
    const float* mib   = (const float*)d_in[18];
    const float* mow   = (const float*)d_in[19];
    const float* mob   = (const float*)d_in[20];
    const float* Wc1   = (const float*)d_in[21];
    const float* bc1   = (const float*)d_in[22];
    const float* Wc2   = (const float*)d_in[23];
    const float* bc2   = (const float*)d_in[24];

    const int N = in_sizes[4];        // 20000
    const int E = in_sizes[2] / 2;    // 320000
    const int SN = (N + (1 << SSHIFT) - 1) >> SSHIFT;   // stripes per node (20)
    const size_t M = (size_t)N * SN;                    // bucket count per branch

    char* p = (char*)d_ws;
    auto carve = [&](size_t bytes) {
        void* r = (void*)p;
        p += (bytes + 255) & ~(size_t)255;
        return r;
    };
    float*          h      = (float*)carve((size_t)2 * N * HH * 4);
    unsigned short* qb     = (unsigned short*)carve((size_t)N * 256 * 2);
    unsigned short* kvb    = (unsigned short*)carve((size_t)N * 512 * 2);
    float*          pooled = (float*)carve((size_t)2 * GG * HH * 4);
    float*          cnt    = (float*)carve((size_t)2 * GG * 4);
    int*            counts = (int*)carve((size_t)2 * M * 4);
    int*            ip2    = (int*)carve((size_t)2 * (M + 1) * 4);
    int*            cursor = (int*)carve((size_t)2 * M * 4);
    int*            srcs   = (int*)carve((size_t)2 * E * 4);
    int*            btot   = (int*)carve((size_t)2 * 1024 * 4);
    unsigned short* panel  = (unsigned short*)carve((size_t)3 * 2 * 832 * 64 * 2);
    unsigned short* panelE = (unsigned short*)carve((size_t)2 * 64 * 256 * 2);

    hipMemsetAsync(pooled, 0, (size_t)2 * GG * HH * 4, stream);
    hipMemsetAsync(cnt, 0, (size_t)2 * GG * 4, stream);
    hipMemsetAsync(counts, 0, (size_t)2 * M * 4, stream);

    k_packw<<<(3 * 832 * 64 + 255) / 256, 256, 0, stream>>>(Wq, Wk, Wv, Ws, panel);
    k_packemb<<<(64 * 256 + 255) / 256, 256, 0, stream>>>(W_emb, panelE);

    const int nb = (int)((M + 1023) / 1024);      // <= 1024 blocks
    k_hist<<<dim3((E + 255) / 256, 2), 256, 0, stream>>>(ei1, ei2, E, counts, SN, M);
    k_scan_part<<<dim3(nb, 2), 1024, 0, stream>>>(counts, M, ip2, btot);
    k_scan_fix<<<dim3(nb, 2), 1024, 0, stream>>>(M, nb, ip2, cursor, btot);
    k_scatter<<<dim3((E + 255) / 256, 2), 256, 0, stream>>>(ei1, ei2, E, cursor, srcs, SN, M);

    k_embed<<<dim3((N + 31) / 32, 2), 256, 0, stream>>>(x1, x2, panelE, b_emb, temb, h, N);

    const int attnGX = min((N + 3) / 4, 2048);
    const int projGX = (N + 31) / 32;

    for (int br = 0; br < 2; ++br) {
        for (int l = 0; l < LLAY; ++l) {
            k_proj<<<projGX, 256, 0, stream>>>(
                h, panel + (size_t)l * 2 * 832 * 64,
                bq + (size_t)l * 256, bk + (size_t)l * 256, bv + (size_t)l * 256, bs + (size_t)l * 64,
                qb, kvb, N, br);
            k_attn<<<attnGX, 256, 0, stream>>>(
                qb, kvb, ip2, srcs, h, N, E, br, SN, M);
        }
    }

    k_pool<<<dim3((N + 31) / 32, 2), 64, 0, stream>>>(h, bat1, bat2, pooled, cnt, N);

    k_head<<<GG, 64, 0, stream>>>(pooled, cnt, miw, mib, mow, mob, Wc1, bc1, Wc2, bc2,
                                  (float*)d_out);
}

// Round 7
// 641.071 us; speedup vs baseline: 1.0190x; 1.0190x over previous
//
#include <hip/hip_runtime.h>
#include <math.h>

#define FF   256
#define HH   64
#define NHEADS 4
#define LLAY 3
#define GG   64
#define CCLS 10
#define SSHIFT 10           // src stripe = src >> 10  (1024 nodes = 1 MB fp16 KV)

typedef __attribute__((ext_vector_type(8))) short short8v;
typedef __attribute__((ext_vector_type(4))) float floatx4;
typedef __attribute__((ext_vector_type(2))) _Float16 h2v;

#if defined(__has_builtin)
#if __has_builtin(__builtin_amdgcn_fdot2)
#define HAS_FDOT2 1
#endif
#endif

__device__ __forceinline__ unsigned short f2bf(float f) {
    unsigned int u = __float_as_uint(f);
    unsigned int r = (u + 0x7fffu + ((u >> 16) & 1u)) >> 16;   // RNE
    return (unsigned short)r;
}
__device__ __forceinline__ float bf2f(unsigned short h) {
    return __uint_as_float((unsigned int)h << 16);
}
__device__ __forceinline__ unsigned short f2h(float f) {
    _Float16 h = (_Float16)f;
    return __builtin_bit_cast(unsigned short, h);
}
__device__ __forceinline__ float2 h2f(unsigned int u) {
    h2v h = __builtin_bit_cast(h2v, u);
    return make_float2((float)h.x, (float)h.y);
}
__device__ __forceinline__ float dot8h(uint4 k, uint4 q) {
#ifdef HAS_FDOT2
    float d = 0.f;
    d = __builtin_amdgcn_fdot2(__builtin_bit_cast(h2v, k.x), __builtin_bit_cast(h2v, q.x), d, false);
    d = __builtin_amdgcn_fdot2(__builtin_bit_cast(h2v, k.y), __builtin_bit_cast(h2v, q.y), d, false);
    d = __builtin_amdgcn_fdot2(__builtin_bit_cast(h2v, k.z), __builtin_bit_cast(h2v, q.z), d, false);
    d = __builtin_amdgcn_fdot2(__builtin_bit_cast(h2v, k.w), __builtin_bit_cast(h2v, q.w), d, false);
    return d;
#else
    float2 k0 = h2f(k.x), k1 = h2f(k.y), k2 = h2f(k.z), k3 = h2f(k.w);
    float2 q0 = h2f(q.x), q1 = h2f(q.y), q2 = h2f(q.z), q3 = h2f(q.w);
    return k0.x*q0.x + k0.y*q0.y + k1.x*q1.x + k1.y*q1.y +
           k2.x*q2.x + k2.y*q2.y + k3.x*q3.x + k3.y*q3.y;
#endif
}

// ---------------------------------------------------------------------------
// Weight packing (bf16 hi/lo panels for MFMA GEMMs)
// ---------------------------------------------------------------------------
__global__ void k_packw(const float* __restrict__ Wq, const float* __restrict__ Wk,
                        const float* __restrict__ Wv, const float* __restrict__ Ws,
                        unsigned short* __restrict__ panel) {
    int idx = blockIdx.x * 256 + threadIdx.x;          // over 3*832*64
    if (idx >= 3 * 832 * 64) return;
    int l = idx / (832 * 64);
    int rem = idx % (832 * 64);
    int c = rem / 64, k = rem % 64;
    float v;
    if (c < 256)      v = Wq[((size_t)l * 64 + k) * 256 + c];
    else if (c < 512) v = Wk[((size_t)l * 64 + k) * 256 + (c - 256)];
    else if (c < 768) v = Wv[((size_t)l * 64 + k) * 256 + (c - 512)];
    else              v = Ws[((size_t)l * 64 + k) * 64 + (c - 768)];
    unsigned short hi = f2bf(v);
    unsigned short lo = f2bf(v - bf2f(hi));
    panel[((size_t)l * 2 + 0) * 832 * 64 + rem] = hi;
    panel[((size_t)l * 2 + 1) * 832 * 64 + rem] = lo;
}

__global__ void k_packemb(const float* __restrict__ W, unsigned short* __restrict__ pE) {
    int idx = blockIdx.x * 256 + threadIdx.x;          // over 64*256
    if (idx >= 64 * 256) return;
    int c = idx / 256, k = idx % 256;
    float v = W[(size_t)k * 64 + c];
    unsigned short hi = f2bf(v);
    unsigned short lo = f2bf(v - bf2f(hi));
    pE[idx] = hi;
    pE[64 * 256 + idx] = lo;
}

// ---------------------------------------------------------------------------
// Stripe-bucketed CSR: key = dst*SN + (src>>SSHIFT). Edges of each node come
// out sorted by src stripe -> the attention sweep has L2 temporal locality.
// ---------------------------------------------------------------------------
__global__ void k_hist(const int* __restrict__ eiA, const int* __restrict__ eiB, int E,
                       int* __restrict__ counts0, int SN, size_t M) {
    int br = blockIdx.y;
    const int* ei = br ? eiB : eiA;
    int* c = counts0 + (size_t)br * M;
    int i = blockIdx.x * blockDim.x + threadIdx.x;
    if (i < E) {
        int src = ei[i], dst = ei[E + i];
        atomicAdd(&c[(size_t)dst * SN + (src >> SSHIFT)], 1);
    }
}

// three-level parallel exclusive scan over M = N*SN entries
__global__ void k_scan_part(const int* __restrict__ counts0, size_t M,
                            int* __restrict__ ip0, int* __restrict__ btot) {
    int br = blockIdx.y, b = blockIdx.x, t = threadIdx.x;
    const int* counts = counts0 + (size_t)br * M;
    int* ip = ip0 + (size_t)br * (M + 1);
    __shared__ int sd[1024];
    size_t i = (size_t)b * 1024 + t;
    int v = (i < M) ? counts[i] : 0;
    sd[t] = v;
    __syncthreads();
    for (int off = 1; off < 1024; off <<= 1) {
        int x = (t >= off) ? sd[t - off] : 0;
        __syncthreads();
        sd[t] += x;
        __syncthreads();
    }
    if (i < M) ip[i] = sd[t] - v;                  // local exclusive
    if (t == 1023) btot[br * 1024 + b] = sd[1023];
}

// scan the per-block totals (nb <= 1024) -> exclusive prefix in btote
__global__ void k_scan_mid(int nb, const int* __restrict__ btot,
                           int* __restrict__ btote) {
    int br = blockIdx.y, t = threadIdx.x;
    __shared__ int sd[1024];
    int v = (t < nb) ? btot[br * 1024 + t] : 0;
    sd[t] = v;
    __syncthreads();
    for (int off = 1; off < 1024; off <<= 1) {
        int x = (t >= off) ? sd[t - off] : 0;
        __syncthreads();
        sd[t] += x;
        __syncthreads();
    }
    if (t < nb) btote[br * 1024 + t] = sd[t] - v;
}

__global__ void k_scan_fix(size_t M, int nb, int* __restrict__ ip0,
                           int* __restrict__ cursor0,
                           const int* __restrict__ btot,
                           const int* __restrict__ btote) {
    int br = blockIdx.y, b = blockIdx.x, t = threadIdx.x;
    int* ip = ip0 + (size_t)br * (M + 1);
    int* cursor = cursor0 + (size_t)br * M;
    int soff = btote[br * 1024 + b];
    if (t == 0 && b == nb - 1) ip[M] = soff + btot[br * 1024 + b];
    size_t i = (size_t)b * 1024 + t;
    if (i < M) {
        int val = ip[i] + soff;
        ip[i] = val;
        cursor[i] = val;
    }
}

__global__ void k_scatter(const int* __restrict__ eiA, const int* __restrict__ eiB, int E,
                          int* __restrict__ cursor0, int* __restrict__ srcs0,
                          int SN, size_t M) {
    int br = blockIdx.y;
    const int* ei = br ? eiB : eiA;
    int* cursor = cursor0 + (size_t)br * M;
    int* srcs = srcs0 + (size_t)br * E;
    int i = blockIdx.x * blockDim.x + threadIdx.x;
    if (i < E) {
        int src = ei[i], dst = ei[E + i];
        int p = atomicAdd(&cursor[(size_t)dst * SN + (src >> SSHIFT)], 1);
        srcs[p] = src;
    }
}

// ---------------------------------------------------------------------------
// Embedding MFMA: h[br] = x @ W_emb + b + temb[br].  M=32/block, both branches.
// ---------------------------------------------------------------------------
__global__ void k_embed(const float* __restrict__ xa, const float* __restrict__ xb,
                        const unsigned short* __restrict__ pE,
                        const float* __restrict__ bemb, const float* __restrict__ temb,
                        float* __restrict__ h0, int N) {
    int br = blockIdx.y;
    const float* x = br ? xb : xa;
    float* h = h0 + (size_t)br * N * HH;
    int t = threadIdx.x, lane = t & 63, wid = t >> 6;
    int arow = lane & 15, kg = lane >> 4;
    int mbase = blockIdx.x * 32;
    int n0 = min(mbase + arow, N - 1);
    int n1 = min(mbase + 16 + arow, N - 1);
    const float* x0 = x + (size_t)n0 * FF + kg * 8;
    const float* x1 = x + (size_t)n1 * FF + kg * 8;
    const unsigned short* bh = pE + (size_t)(wid * 16 + arow) * FF + kg * 8;
    const unsigned short* bl = bh + 64 * FF;
    floatx4 acc0 = {0.f, 0.f, 0.f, 0.f}, acc1 = {0.f, 0.f, 0.f, 0.f};
#pragma unroll
    for (int ks = 0; ks < 8; ++ks) {
        const float4* p0 = reinterpret_cast<const float4*>(x0 + ks * 32);
        float4 f00 = p0[0], f01 = p0[1];
        const float4* p1 = reinterpret_cast<const float4*>(x1 + ks * 32);
        float4 f10 = p1[0], f11 = p1[1];
        float v0[8] = {f00.x, f00.y, f00.z, f00.w, f01.x, f01.y, f01.z, f01.w};
        float v1[8] = {f10.x, f10.y, f10.z, f10.w, f11.x, f11.y, f11.z, f11.w};
        short8v a0h, a0l, a1h, a1l;
#pragma unroll
        for (int i = 0; i < 8; ++i) {
            unsigned short h0v = f2bf(v0[i]);
            a0h[i] = (short)h0v; a0l[i] = (short)f2bf(v0[i] - bf2f(h0v));
            unsigned short h1v = f2bf(v1[i]);
            a1h[i] = (short)h1v; a1l[i] = (short)f2bf(v1[i] - bf2f(h1v));
        }
        short8v bhv = *reinterpret_cast<const short8v*>(bh + ks * 32);
        short8v blv = *reinterpret_cast<const short8v*>(bl + ks * 32);
        acc0 = __builtin_amdgcn_mfma_f32_16x16x32_bf16(a0h, bhv, acc0, 0, 0, 0);
        acc0 = __builtin_amdgcn_mfma_f32_16x16x32_bf16(a0l, bhv, acc0, 0, 0, 0);
        acc0 = __builtin_amdgcn_mfma_f32_16x16x32_bf16(a0h, blv, acc0, 0, 0, 0);
        acc1 = __builtin_amdgcn_mfma_f32_16x16x32_bf16(a1h, bhv, acc1, 0, 0, 0);
        acc1 = __builtin_amdgcn_mfma_f32_16x16x32_bf16(a1l, bhv, acc1, 0, 0, 0);
        acc1 = __builtin_amdgcn_mfma_f32_16x16x32_bf16(a1h, blv, acc1, 0, 0, 0);
    }
    int col = wid * 16 + (lane & 15);
    float bias = bemb[col] + temb[(size_t)br * HH + col];
#pragma unroll
    for (int r = 0; r < 4; ++r) {
        int row0 = mbase + kg * 4 + r;
        if (row0 < N) h[(size_t)row0 * HH + col] = acc0[r] + bias;
        int row1 = mbase + 16 + kg * 4 + r;
        if (row1 < N) h[(size_t)row1 * HH + col] = acc1[r] + bias;
    }
}

// ---------------------------------------------------------------------------
// Projection MFMA: q/k/v (fp16) + skip (written back into h, f32).
// ---------------------------------------------------------------------------
__global__ void k_proj(float* __restrict__ h0, const unsigned short* __restrict__ panel,
                       const float* __restrict__ bq, const float* __restrict__ bk,
                       const float* __restrict__ bv, const float* __restrict__ bs,
                       unsigned short* __restrict__ q, unsigned short* __restrict__ kv,
                       int N, int br) {
    float* h = h0 + (size_t)br * N * HH;
    int t = threadIdx.x, lane = t & 63, wid = t >> 6;
    int arow = lane & 15, kg = lane >> 4;
    int mbase = blockIdx.x * 32;

    short8v Ah[2][2], Al[2][2];
#pragma unroll
    for (int mt = 0; mt < 2; ++mt) {
        int node = min(mbase + mt * 16 + arow, N - 1);
        const float* src = h + (size_t)node * HH + kg * 8;
#pragma unroll
        for (int ks = 0; ks < 2; ++ks) {
            const float4* pp = reinterpret_cast<const float4*>(src + ks * 32);
            float4 fa = pp[0], fb = pp[1];
            float v[8] = {fa.x, fa.y, fa.z, fa.w, fb.x, fb.y, fb.z, fb.w};
#pragma unroll
            for (int i = 0; i < 8; ++i) {
                unsigned short hi = f2bf(v[i]);
                Ah[mt][ks][i] = (short)hi;
                Al[mt][ks][i] = (short)f2bf(v[i] - bf2f(hi));
            }
        }
    }
    // all waves have consumed h before skip columns overwrite it below
    __syncthreads();

    const unsigned short* ph = panel;
    const unsigned short* pl = panel + 832 * 64;
#pragma unroll
    for (int j = 0; j < 13; ++j) {
        int nt = wid * 13 + j;
        size_t boff = (size_t)(nt * 16 + arow) * 64 + kg * 8;
        floatx4 acc0 = {0.f, 0.f, 0.f, 0.f}, acc1 = {0.f, 0.f, 0.f, 0.f};
#pragma unroll
        for (int ks = 0; ks < 2; ++ks) {
            short8v bh = *reinterpret_cast<const short8v*>(ph + boff + ks * 32);
            short8v bl = *reinterpret_cast<const short8v*>(pl + boff + ks * 32);
            acc0 = __builtin_amdgcn_mfma_f32_16x16x32_bf16(Ah[0][ks], bh, acc0, 0, 0, 0);
            acc0 = __builtin_amdgcn_mfma_f32_16x16x32_bf16(Al[0][ks], bh, acc0, 0, 0, 0);
            acc0 = __builtin_amdgcn_mfma_f32_16x16x32_bf16(Ah[0][ks], bl, acc0, 0, 0, 0);
            acc1 = __builtin_amdgcn_mfma_f32_16x16x32_bf16(Ah[1][ks], bh, acc1, 0, 0, 0);
            acc1 = __builtin_amdgcn_mfma_f32_16x16x32_bf16(Al[1][ks], bh, acc1, 0, 0, 0);
            acc1 = __builtin_amdgcn_mfma_f32_16x16x32_bf16(Ah[1][ks], bl, acc1, 0, 0, 0);
        }
        int col = nt * 16 + (lane & 15);
        float bias;
        if (col < 256) bias = bq[col];
        else if (col < 512) bias = bk[col - 256];
        else if (col < 768) bias = bv[col - 512];
        else bias = bs[col - 768];

        auto store_tile = [&](const floatx4& acc, int mrow0) {
#pragma unroll
            for (int r = 0; r < 4; ++r) {
                int node = mrow0 + kg * 4 + r;
                if (node < N) {
                    float val = acc[r] + bias;
                    if (col < 256)      q[(size_t)node * 256 + col] = f2h(val);
                    else if (col < 512) kv[(size_t)node * 512 + (col - 256)] = f2h(val);
                    else if (col < 768) kv[(size_t)node * 512 + 256 + (col - 512)] = f2h(val);
                    else                h[(size_t)node * HH + (col - 768)] = val;  // skip
                }
            }
        };
        store_tile(acc0, mbase);
        store_tile(acc1, mbase + 16);
    }
}

// ---------------------------------------------------------------------------
// Attention aggregate. One wave per node; 32 lanes per edge (2 edges/pass).
// 16-edge chunks: 8 K+V gathers in flight per half before any compute.
// Edges are src-stripe-sorted -> L2-resident gathers.
// ---------------------------------------------------------------------------
__global__ void k_attn(const unsigned short* __restrict__ qb,
                       const unsigned short* __restrict__ kvb,
                       const int* __restrict__ ip0, const int* __restrict__ srcs0,
                       float* __restrict__ h0, int N, int E, int br, int SN, size_t M) {
    const int* ip2 = ip0 + (size_t)br * (M + 1);
    const int* srcs = srcs0 + (size_t)br * E;
    float* h = h0 + (size_t)br * N * HH;

    int t = threadIdx.x;
    int lane = t & 63;
    int half = lane >> 5;
    int il = lane & 31;
    int o = il & 7;
    int elemoff = (il >> 3) * 64 + o * 8;

    int wvg = blockIdx.x * 4 + (t >> 6);
    int nw = gridDim.x * 4;
    for (int n = wvg; n < N; n += nw) {
        int beg = ip2[(size_t)n * SN], end = ip2[(size_t)n * SN + SN];
        if (end == beg) {
            if (lane < 8) {
                float4 s0 = *reinterpret_cast<const float4*>(&h[(size_t)n * HH + o * 8]);
                float4 s1 = *reinterpret_cast<const float4*>(&h[(size_t)n * HH + o * 8 + 4]);
                s0.x = fmaxf(s0.x, 0.f); s0.y = fmaxf(s0.y, 0.f);
                s0.z = fmaxf(s0.z, 0.f); s0.w = fmaxf(s0.w, 0.f);
                s1.x = fmaxf(s1.x, 0.f); s1.y = fmaxf(s1.y, 0.f);
                s1.z = fmaxf(s1.z, 0.f); s1.w = fmaxf(s1.w, 0.f);
                *reinterpret_cast<float4*>(&h[(size_t)n * HH + o * 8]) = s0;
                *reinterpret_cast<float4*>(&h[(size_t)n * HH + o * 8 + 4]) = s1;
            }
            continue;
        }
        uint4 q4 = *reinterpret_cast<const uint4*>(qb + (size_t)n * 256 + elemoff);
        float m = -INFINITY, s = 0.f;
        float a0=0.f,a1=0.f,a2=0.f,a3=0.f,a4=0.f,a5=0.f,a6=0.f,a7=0.f;

        for (int e0 = beg; e0 < end; e0 += 16) {
            uint4 kk[8], vv[8];
            bool vd[8];
#pragma unroll
            for (int i = 0; i < 8; ++i) {
                int ei = e0 + 2 * i + half;
                bool ok = ei < end;
                vd[i] = ok;
                int src = srcs[ok ? ei : beg];
                const unsigned short* kb = kvb + ((size_t)src << 9) + elemoff;
                kk[i] = *reinterpret_cast<const uint4*>(kb);
                vv[i] = *reinterpret_cast<const uint4*>(kb + 256);
            }
            float lg[8];
#pragma unroll
            for (int i = 0; i < 8; ++i) {
                float d = dot8h(kk[i], q4);
                d += __shfl_xor(d, 1);
                d += __shfl_xor(d, 2);
                d += __shfl_xor(d, 4);
                lg[i] = vd[i] ? d * 0.125f : -INFINITY;
            }
            float cm = fmaxf(fmaxf(fmaxf(lg[0], lg[1]), fmaxf(lg[2], lg[3])),
                             fmaxf(fmaxf(lg[4], lg[5]), fmaxf(lg[6], lg[7])));
            float mn = fmaxf(m, cm);
            float rs = (m == -INFINITY) ? 0.f : __expf(m - mn);
            s *= rs;
            a0*=rs; a1*=rs; a2*=rs; a3*=rs; a4*=rs; a5*=rs; a6*=rs; a7*=rs;
            m = mn;
#pragma unroll
            for (int i = 0; i < 8; ++i) {
                float p = vd[i] ? __expf(lg[i] - mn) : 0.f;
                s += p;
                float2 v01 = h2f(vv[i].x), v23 = h2f(vv[i].y);
                float2 v45 = h2f(vv[i].z), v67 = h2f(vv[i].w);
                a0 += p * v01.x; a1 += p * v01.y; a2 += p * v23.x; a3 += p * v23.y;
                a4 += p * v45.x; a5 += p * v45.y; a6 += p * v67.x; a7 += p * v67.y;
            }
        }
        // merge the two halves (independent online softmaxes)
        float mo = __shfl_xor(m, 32);
        float mt2 = fmaxf(m, mo);
        float myscale = (m == -INFINITY) ? 0.f : __expf(m - mt2);
        float ss = s * myscale;
        float st = ss + __shfl_xor(ss, 32);
        float inv = 1.f / st;
        a0 *= myscale; a0 += __shfl_xor(a0, 32);
        a1 *= myscale; a1 += __shfl_xor(a1, 32);
        a2 *= myscale; a2 += __shfl_xor(a2, 32);
        a3 *= myscale; a3 += __shfl_xor(a3, 32);
        a4 *= myscale; a4 += __shfl_xor(a4, 32);
        a5 *= myscale; a5 += __shfl_xor(a5, 32);
        a6 *= myscale; a6 += __shfl_xor(a6, 32);
        a7 *= myscale; a7 += __shfl_xor(a7, 32);
        a0 *= inv; a1 *= inv; a2 *= inv; a3 *= inv;
        a4 *= inv; a5 *= inv; a6 *= inv; a7 *= inv;
        // head mean (sum over head bits 3,4 of il)
        a0 += __shfl_xor(a0, 8);  a0 += __shfl_xor(a0, 16);
        a1 += __shfl_xor(a1, 8);  a1 += __shfl_xor(a1, 16);
        a2 += __shfl_xor(a2, 8);  a2 += __shfl_xor(a2, 16);
        a3 += __shfl_xor(a3, 8);  a3 += __shfl_xor(a3, 16);
        a4 += __shfl_xor(a4, 8);  a4 += __shfl_xor(a4, 16);
        a5 += __shfl_xor(a5, 8);  a5 += __shfl_xor(a5, 16);
        a6 += __shfl_xor(a6, 8);  a6 += __shfl_xor(a6, 16);
        a7 += __shfl_xor(a7, 8);  a7 += __shfl_xor(a7, 16);
        if (lane < 8) {
            float4 s0 = *reinterpret_cast<const float4*>(&h[(size_t)n * HH + o * 8]);
            float4 s1 = *reinterpret_cast<const float4*>(&h[(size_t)n * HH + o * 8 + 4]);
            float4 r0, r1;
            r0.x = fmaxf(0.25f * a0 + s0.x, 0.f);
            r0.y = fmaxf(0.25f * a1 + s0.y, 0.f);
            r0.z = fmaxf(0.25f * a2 + s0.z, 0.f);
            r0.w = fmaxf(0.25f * a3 + s0.w, 0.f);
            r1.x = fmaxf(0.25f * a4 + s1.x, 0.f);
            r1.y = fmaxf(0.25f * a5 + s1.y, 0.f);
            r1.z = fmaxf(0.25f * a6 + s1.z, 0.f);
            r1.w = fmaxf(0.25f * a7 + s1.w, 0.f);
            *reinterpret_cast<float4*>(&h[(size_t)n * HH + o * 8]) = r0;
            *reinterpret_cast<float4*>(&h[(size_t)n * HH + o * 8 + 4]) = r1;
        }
    }
}

// ---------------------------------------------------------------------------
// Mean pool (batch sorted, run-length accumulate), both branches
// ---------------------------------------------------------------------------
__global__ void k_pool(const float* __restrict__ h0, const int* __restrict__ batA,
                       const int* __restrict__ batB,
                       float* __restrict__ pooled, float* __restrict__ cnt, int N) {
    int br = blockIdx.y;
    const float* h = h0 + (size_t)br * N * HH;
    const int* batch = br ? batB : batA;
    float* pb = pooled + (size_t)br * GG * HH;
    float* cb = cnt + (size_t)br * GG;
    int j = threadIdx.x;
    int n0 = blockIdx.x * 32;
    int n1 = min(n0 + 32, N);
    if (n0 >= N) return;
    float acc = 0.f;
    int c = 0;
    int gcur = batch[n0];
    for (int n = n0; n < n1; ++n) {
        int g = batch[n];
        if (g != gcur) {
            atomicAdd(&pb[gcur * HH + j], acc);
            if (j == 0) atomicAdd(&cb[gcur], (float)c);
            acc = 0.f; c = 0; gcur = g;
        }
        acc += h[(size_t)n * HH + j];
        ++c;
    }
    atomicAdd(&pb[gcur * HH + j], acc);
    if (j == 0) atomicAdd(&cb[gcur], (float)c);
}

// ---------------------------------------------------------------------------
// Head: mean-pool finalize, MHA over seq=2, mean, classifier. Block per graph.
// ---------------------------------------------------------------------------
__global__ void k_head(const float* __restrict__ pooled, const float* __restrict__ cnt,
                       const float* __restrict__ in_w, const float* __restrict__ in_b,
                       const float* __restrict__ out_w, const float* __restrict__ out_b,
                       const float* __restrict__ Wc1, const float* __restrict__ bc1,
                       const float* __restrict__ Wc2, const float* __restrict__ bc2,
                       float* __restrict__ out) {
    int g = blockIdx.x;
    int t = threadIdx.x;
    __shared__ float xs[2][HH];
    __shared__ float qkvs[2][3 * HH];
    __shared__ float sc[2][2][NHEADS];
    __shared__ float os[2][HH];
    __shared__ float xf[HH];
    __shared__ float r1[HH / 2];

    for (int s = 0; s < 2; ++s) {
        float c = fmaxf(cnt[s * GG + g], 1.f);
        xs[s][t] = pooled[(size_t)s * GG * HH + g * HH + t] / c;
    }
    __syncthreads();
    for (int idx = t; idx < 2 * 192; idx += 64) {
        int s = idx / 192, i = idx % 192;
        float a = in_b[i];
#pragma unroll 8
        for (int j = 0; j < HH; ++j) a += xs[s][j] * in_w[i * HH + j];
        qkvs[s][i] = a;
    }
    __syncthreads();
    if (t < 16) {
        int s1 = t >> 3, s2 = (t >> 2) & 1, hh = t & 3;
        float a = 0.f;
#pragma unroll
        for (int d = 0; d < 16; ++d) a += qkvs[s1][hh * 16 + d] * qkvs[s2][HH + hh * 16 + d];
        sc[s1][s2][hh] = a * 0.25f;
    }
    __syncthreads();
    {
        int hh = t >> 4;
        for (int s1 = 0; s1 < 2; ++s1) {
            float a0 = sc[s1][0][hh], a1 = sc[s1][1][hh];
            float mx = fmaxf(a0, a1);
            float e0 = __expf(a0 - mx), e1 = __expf(a1 - mx);
            float inv = 1.f / (e0 + e1);
            os[s1][t] = (e0 * inv) * qkvs[0][2 * HH + t] + (e1 * inv) * qkvs[1][2 * HH + t];
        }
    }
    __syncthreads();
    {
        float acc0 = 0.f, acc1 = 0.f;
#pragma unroll 8
        for (int k2 = 0; k2 < HH; ++k2) {
            float w = out_w[t * HH + k2];
            acc0 += os[0][k2] * w;
            acc1 += os[1][k2] * w;
        }
        xf[t] = 0.5f * (acc0 + acc1) + out_b[t];
    }
    __syncthreads();
    if (t < 32) {
        float a = bc1[t];
#pragma unroll 8
        for (int j = 0; j < HH; ++j) a += xf[j] * Wc1[j * 32 + t];
        r1[t] = fmaxf(a, 0.f);
    }
    __syncthreads();
    if (t < CCLS) {
        float a = bc2[t];
#pragma unroll
        for (int j2 = 0; j2 < 32; ++j2) a += r1[j2] * Wc2[j2 * CCLS + t];
        out[g * CCLS + t] = a;
    }
}

// ---------------------------------------------------------------------------
extern "C" void kernel_launch(void* const* d_in, const int* in_sizes, int n_in,
                              void* d_out, int out_size, void* d_ws, size_t ws_size,
                              hipStream_t stream) {
    const float* x1    = (const float*)d_in[0];
    const float* x2    = (const float*)d_in[1];
    const int*   ei1   = (const int*)d_in[2];
    const int*   ei2   = (const int*)d_in[3];
    const int*   bat1  = (const int*)d_in[4];
    const int*   bat2  = (const int*)d_in[5];
    const float* W_emb = (const float*)d_in[6];
    const float* b_emb = (const float*)d_in[7];
    const float* temb  = (const float*)d_in[8];
    const float* Wq    = (const float*)d_in[9];
    const float* bq    = (const float*)d_in[10];
    const float* Wk    = (const float*)d_in[11];
    const float* bk    = (const float*)d_in[12];
    const float* Wv    = (const float*)d_in[13];
    const float* bv    = (const float*)d_in[14];
    const float* Ws    = (const float*)d_in[15];
    const float* bs    = (const float*)d_in[16];
    const float* miw   = (const float*)d_in[17];
    const float* mib   = (const float*)d_in[18];
    const float* mow   = (const float*)d_in[19];
    const float* mob   = (const float*)d_in[20];
    const float* Wc1   = (const float*)d_in[21];
    const float* bc1   = (const float*)d_in[22];
    const float* Wc2   = (const float*)d_in[23];
    const float* bc2   = (const float*)d_in[24];

    const int N = in_sizes[4];        // 20000
    const int E = in_sizes[2] / 2;    // 320000
    const int SN = (N + (1 << SSHIFT) - 1) >> SSHIFT;   // stripes per node (20)
    const size_t M = (size_t)N * SN;                    // bucket count per branch

    char* p = (char*)d_ws;
    auto carve = [&](size_t bytes) {
        void* r = (void*)p;
        p += (bytes + 255) & ~(size_t)255;
        return r;
    };
    float*          h      = (float*)carve((size_t)2 * N * HH * 4);
    unsigned short* qb     = (unsigned short*)carve((size_t)N * 256 * 2);
    unsigned short* kvb    = (unsigned short*)carve((size_t)N * 512 * 2);
    float*          pooled = (float*)carve((size_t)2 * GG * HH * 4);
    float*          cnt    = (float*)carve((size_t)2 * GG * 4);
    int*            counts = (int*)carve((size_t)2 * M * 4);
    int*            ip2    = (int*)carve((size_t)2 * (M + 1) * 4);
    int*            cursor = (int*)carve((size_t)2 * M * 4);
    int*            srcs   = (int*)carve((size_t)2 * E * 4);
    int*            btot   = (int*)carve((size_t)2 * 1024 * 4);
    int*            btote  = (int*)carve((size_t)2 * 1024 * 4);
    unsigned short* panel  = (unsigned short*)carve((size_t)3 * 2 * 832 * 64 * 2);
    unsigned short* panelE = (unsigned short*)carve((size_t)2 * 64 * 256 * 2);

    hipMemsetAsync(pooled, 0, (size_t)2 * GG * HH * 4, stream);
    hipMemsetAsync(cnt, 0, (size_t)2 * GG * 4, stream);
    hipMemsetAsync(counts, 0, (size_t)2 * M * 4, stream);

    k_packw<<<(3 * 832 * 64 + 255) / 256, 256, 0, stream>>>(Wq, Wk, Wv, Ws, panel);
    k_packemb<<<(64 * 256 + 255) / 256, 256, 0, stream>>>(W_emb, panelE);

    const int nb = (int)((M + 1023) / 1024);      // <= 1024 blocks
    k_hist<<<dim3((E + 255) / 256, 2), 256, 0, stream>>>(ei1, ei2, E, counts, SN, M);
    k_scan_part<<<dim3(nb, 2), 1024, 0, stream>>>(counts, M, ip2, btot);
    k_scan_mid<<<dim3(1, 2), 1024, 0, stream>>>(nb, btot, btote);
    k_scan_fix<<<dim3(nb, 2), 1024, 0, stream>>>(M, nb, ip2, cursor, btot, btote);
    k_scatter<<<dim3((E + 255) / 256, 2), 256, 0, stream>>>(ei1, ei2, E, cursor, srcs, SN, M);

    k_embed<<<dim3((N + 31) / 32, 2), 256, 0, stream>>>(x1, x2, panelE, b_emb, temb, h, N);

    const int attnGX = min((N + 3) / 4, 2048);
    const int projGX = (N + 31) / 32;

    for (int br = 0; br < 2; ++br) {
        for (int l = 0; l < LLAY; ++l) {
            k_proj<<<projGX, 256, 0, stream>>>(
                h, panel + (size_t)l * 2 * 832 * 64,
                bq + (size_t)l * 256, bk + (size_t)l * 256, bv + (size_t)l * 256, bs + (size_t)l * 64,
                qb, kvb, N, br);
            k_attn<<<attnGX, 256, 0, stream>>>(
                qb, kvb, ip2, srcs, h, N, E, br, SN, M);
        }
    }

    k_pool<<<dim3((N + 31) / 32, 2), 64, 0, stream>>>(h, bat1, bat2, pooled, cnt, N);

    k_head<<<GG, 64, 0, stream>>>(pooled, cnt, miw, mib, mow, mob, Wc1, bc1, Wc2, bc2,
                                  (float*)d_out);
}

// Round 8
// 601.770 us; speedup vs baseline: 1.0855x; 1.0653x over previous
//
#include <hip/hip_runtime.h>
#include <math.h>

#define FF   256
#define HH   64
#define NHEADS 4
#define LLAY 3
#define GG   64
#define CCLS 10

typedef __attribute__((ext_vector_type(8))) short short8v;
typedef __attribute__((ext_vector_type(4))) float floatx4;
typedef __attribute__((ext_vector_type(2))) _Float16 h2v;

#if defined(__has_builtin)
#if __has_builtin(__builtin_amdgcn_fdot2)
#define HAS_FDOT2 1
#endif
#endif

__device__ __forceinline__ unsigned short f2bf(float f) {
    unsigned int u = __float_as_uint(f);
    unsigned int r = (u + 0x7fffu + ((u >> 16) & 1u)) >> 16;   // RNE
    return (unsigned short)r;
}
__device__ __forceinline__ float bf2f(unsigned short h) {
    return __uint_as_float((unsigned int)h << 16);
}
__device__ __forceinline__ unsigned short f2h(float f) {
    _Float16 h = (_Float16)f;
    return __builtin_bit_cast(unsigned short, h);
}
__device__ __forceinline__ float2 h2f(unsigned int u) {
    h2v h = __builtin_bit_cast(h2v, u);
    return make_float2((float)h.x, (float)h.y);
}
__device__ __forceinline__ float dot8h(uint4 k, uint4 q) {
#ifdef HAS_FDOT2
    float d = 0.f;
    d = __builtin_amdgcn_fdot2(__builtin_bit_cast(h2v, k.x), __builtin_bit_cast(h2v, q.x), d, false);
    d = __builtin_amdgcn_fdot2(__builtin_bit_cast(h2v, k.y), __builtin_bit_cast(h2v, q.y), d, false);
    d = __builtin_amdgcn_fdot2(__builtin_bit_cast(h2v, k.z), __builtin_bit_cast(h2v, q.z), d, false);
    d = __builtin_amdgcn_fdot2(__builtin_bit_cast(h2v, k.w), __builtin_bit_cast(h2v, q.w), d, false);
    return d;
#else
    float2 k0 = h2f(k.x), k1 = h2f(k.y), k2 = h2f(k.z), k3 = h2f(k.w);
    float2 q0 = h2f(q.x), q1 = h2f(q.y), q2 = h2f(q.z), q3 = h2f(q.w);
    return k0.x*q0.x + k0.y*q0.y + k1.x*q1.x + k1.y*q1.y +
           k2.x*q2.x + k2.y*q2.y + k3.x*q3.x + k3.y*q3.y;
#endif
}

// ---------------------------------------------------------------------------
// Weight packing (bf16 hi/lo panels), proj + embed fused in one kernel.
// panel: per layer [2(hi/lo)][832 cols][64 k]; panelE: [2][64 cols][256 k]
// ---------------------------------------------------------------------------
__global__ void k_pack(const float* __restrict__ Wq, const float* __restrict__ Wk,
                       const float* __restrict__ Wv, const float* __restrict__ Ws,
                       const float* __restrict__ We,
                       unsigned short* __restrict__ panel, unsigned short* __restrict__ pE) {
    int idx = blockIdx.x * 256 + threadIdx.x;
    if (idx < 3 * 832 * 64) {
        int l = idx / (832 * 64);
        int rem = idx % (832 * 64);
        int c = rem / 64, k = rem % 64;
        float v;
        if (c < 256)      v = Wq[((size_t)l * 64 + k) * 256 + c];
        else if (c < 512) v = Wk[((size_t)l * 64 + k) * 256 + (c - 256)];
        else if (c < 768) v = Wv[((size_t)l * 64 + k) * 256 + (c - 512)];
        else              v = Ws[((size_t)l * 64 + k) * 64 + (c - 768)];
        unsigned short hi = f2bf(v);
        unsigned short lo = f2bf(v - bf2f(hi));
        panel[((size_t)l * 2 + 0) * 832 * 64 + rem] = hi;
        panel[((size_t)l * 2 + 1) * 832 * 64 + rem] = lo;
    } else {
        int e = idx - 3 * 832 * 64;
        if (e >= 64 * 256) return;
        int c = e / 256, k = e % 256;
        float v = We[(size_t)k * 64 + c];
        unsigned short hi = f2bf(v);
        unsigned short lo = f2bf(v - bf2f(hi));
        pE[e] = hi;
        pE[64 * 256 + e] = lo;
    }
}

// ---------------------------------------------------------------------------
// Simple dst-CSR (N buckets), both branches (br = blockIdx.y)
// ---------------------------------------------------------------------------
__global__ void k_hist(const int* __restrict__ eiA, const int* __restrict__ eiB, int E,
                       int* __restrict__ counts0, int N) {
    int br = blockIdx.y;
    const int* dst = (br ? eiB : eiA) + E;
    int* c = counts0 + (size_t)br * N;
    int i = blockIdx.x * blockDim.x + threadIdx.x;
    if (i < E) atomicAdd(&c[dst[i]], 1);
}

__global__ void k_scan_part(const int* __restrict__ counts0, int N,
                            int* __restrict__ ip0, int* __restrict__ btot) {
    int br = blockIdx.y, b = blockIdx.x, t = threadIdx.x;
    const int* counts = counts0 + (size_t)br * N;
    int* ip = ip0 + (size_t)br * (N + 1);
    __shared__ int sd[1024];
    int i = b * 1024 + t;
    int v = (i < N) ? counts[i] : 0;
    sd[t] = v;
    __syncthreads();
    for (int off = 1; off < 1024; off <<= 1) {
        int x = (t >= off) ? sd[t - off] : 0;
        __syncthreads();
        sd[t] += x;
        __syncthreads();
    }
    if (i < N) ip[i] = sd[t] - v;
    if (t == 1023) btot[br * 1024 + b] = sd[1023];
}

__global__ void k_scan_mid(int nb, const int* __restrict__ btot, int* __restrict__ btote) {
    int br = blockIdx.y, t = threadIdx.x;
    __shared__ int sd[1024];
    int v = (t < nb) ? btot[br * 1024 + t] : 0;
    sd[t] = v;
    __syncthreads();
    for (int off = 1; off < 1024; off <<= 1) {
        int x = (t >= off) ? sd[t - off] : 0;
        __syncthreads();
        sd[t] += x;
        __syncthreads();
    }
    if (t < nb) btote[br * 1024 + t] = sd[t] - v;
}

__global__ void k_scan_fix(int N, int nb, int* __restrict__ ip0, int* __restrict__ cursor0,
                           const int* __restrict__ btot, const int* __restrict__ btote) {
    int br = blockIdx.y, b = blockIdx.x, t = threadIdx.x;
    int* ip = ip0 + (size_t)br * (N + 1);
    int* cursor = cursor0 + (size_t)br * N;
    int soff = btote[br * 1024 + b];
    if (t == 0 && b == nb - 1) ip[N] = soff + btot[br * 1024 + b];
    int i = b * 1024 + t;
    if (i < N) {
        int val = ip[i] + soff;
        ip[i] = val;
        cursor[i] = val;
    }
}

__global__ void k_scatter(const int* __restrict__ eiA, const int* __restrict__ eiB, int E,
                          int* __restrict__ cursor0, int* __restrict__ srcs0, int N) {
    int br = blockIdx.y;
    const int* ei = br ? eiB : eiA;
    int* cursor = cursor0 + (size_t)br * N;
    int* srcs = srcs0 + (size_t)br * E;
    int i = blockIdx.x * blockDim.x + threadIdx.x;
    if (i < E) {
        int p = atomicAdd(&cursor[ei[E + i]], 1);
        srcs[p] = ei[i];
    }
}

// ---------------------------------------------------------------------------
// Fused embed + layer-0 projection. 32 nodes/block, 256 threads.
// Embed result lives only in LDS (no h round-trip). Writes q/kv (fp16) and
// skip into h (f32).
// ---------------------------------------------------------------------------
__global__ void k_embed_proj(const float* __restrict__ xa, const float* __restrict__ xb,
                             const unsigned short* __restrict__ pE,
                             const float* __restrict__ bemb, const float* __restrict__ temb,
                             const unsigned short* __restrict__ panel,
                             const float* __restrict__ bq, const float* __restrict__ bk,
                             const float* __restrict__ bv, const float* __restrict__ bs,
                             float* __restrict__ h0, unsigned short* __restrict__ qb0,
                             unsigned short* __restrict__ kvb0, int N, int brBase) {
    int slot = blockIdx.y;
    int br = brBase + slot;
    const float* x = br ? xb : xa;
    float* h = h0 + (size_t)br * N * HH;
    unsigned short* q = qb0 + (size_t)slot * N * 256;
    unsigned short* kv = kvb0 + (size_t)slot * N * 512;

    __shared__ float hs[32][68];   // +4 pad: rows 16B-aligned, low bank conflict
    int t = threadIdx.x, lane = t & 63, wid = t >> 6;
    int arow = lane & 15, kg = lane >> 4;
    int mbase = blockIdx.x * 32;

    // ---- embed (MFMA, bf16x3 split) ----
    {
        int n0 = min(mbase + arow, N - 1);
        int n1 = min(mbase + 16 + arow, N - 1);
        const float* x0 = x + (size_t)n0 * FF + kg * 8;
        const float* x1 = x + (size_t)n1 * FF + kg * 8;
        const unsigned short* bh = pE + (size_t)(wid * 16 + arow) * FF + kg * 8;
        const unsigned short* bl = bh + 64 * FF;
        floatx4 acc0 = {0.f, 0.f, 0.f, 0.f}, acc1 = {0.f, 0.f, 0.f, 0.f};
#pragma unroll
        for (int ks = 0; ks < 8; ++ks) {
            const float4* p0 = reinterpret_cast<const float4*>(x0 + ks * 32);
            float4 f00 = p0[0], f01 = p0[1];
            const float4* p1 = reinterpret_cast<const float4*>(x1 + ks * 32);
            float4 f10 = p1[0], f11 = p1[1];
            float v0[8] = {f00.x, f00.y, f00.z, f00.w, f01.x, f01.y, f01.z, f01.w};
            float v1[8] = {f10.x, f10.y, f10.z, f10.w, f11.x, f11.y, f11.z, f11.w};
            short8v a0h, a0l, a1h, a1l;
#pragma unroll
            for (int i = 0; i < 8; ++i) {
                unsigned short h0v = f2bf(v0[i]);
                a0h[i] = (short)h0v; a0l[i] = (short)f2bf(v0[i] - bf2f(h0v));
                unsigned short h1v = f2bf(v1[i]);
                a1h[i] = (short)h1v; a1l[i] = (short)f2bf(v1[i] - bf2f(h1v));
            }
            short8v bhv = *reinterpret_cast<const short8v*>(bh + ks * 32);
            short8v blv = *reinterpret_cast<const short8v*>(bl + ks * 32);
            acc0 = __builtin_amdgcn_mfma_f32_16x16x32_bf16(a0h, bhv, acc0, 0, 0, 0);
            acc0 = __builtin_amdgcn_mfma_f32_16x16x32_bf16(a0l, bhv, acc0, 0, 0, 0);
            acc0 = __builtin_amdgcn_mfma_f32_16x16x32_bf16(a0h, blv, acc0, 0, 0, 0);
            acc1 = __builtin_amdgcn_mfma_f32_16x16x32_bf16(a1h, bhv, acc1, 0, 0, 0);
            acc1 = __builtin_amdgcn_mfma_f32_16x16x32_bf16(a1l, bhv, acc1, 0, 0, 0);
            acc1 = __builtin_amdgcn_mfma_f32_16x16x32_bf16(a1h, blv, acc1, 0, 0, 0);
        }
        int col = wid * 16 + arow;
        float bias = bemb[col] + temb[(size_t)br * HH + col];
#pragma unroll
        for (int r = 0; r < 4; ++r) {
            hs[kg * 4 + r][col] = acc0[r] + bias;
            hs[16 + kg * 4 + r][col] = acc1[r] + bias;
        }
    }
    __syncthreads();

    // ---- layer-0 projection from LDS ----
    short8v Ah[2][2], Al[2][2];
#pragma unroll
    for (int mt = 0; mt < 2; ++mt) {
#pragma unroll
        for (int ks = 0; ks < 2; ++ks) {
            const float4* pp = reinterpret_cast<const float4*>(&hs[mt * 16 + arow][ks * 32 + kg * 8]);
            float4 fa = pp[0], fb = pp[1];
            float v[8] = {fa.x, fa.y, fa.z, fa.w, fb.x, fb.y, fb.z, fb.w};
#pragma unroll
            for (int i = 0; i < 8; ++i) {
                unsigned short hi = f2bf(v[i]);
                Ah[mt][ks][i] = (short)hi;
                Al[mt][ks][i] = (short)f2bf(v[i] - bf2f(hi));
            }
        }
    }
    const unsigned short* ph = panel;
    const unsigned short* pl = panel + 832 * 64;
#pragma unroll
    for (int j = 0; j < 13; ++j) {
        int nt = wid * 13 + j;
        size_t boff = (size_t)(nt * 16 + arow) * 64 + kg * 8;
        floatx4 acc0 = {0.f, 0.f, 0.f, 0.f}, acc1 = {0.f, 0.f, 0.f, 0.f};
#pragma unroll
        for (int ks = 0; ks < 2; ++ks) {
            short8v bh = *reinterpret_cast<const short8v*>(ph + boff + ks * 32);
            short8v bl = *reinterpret_cast<const short8v*>(pl + boff + ks * 32);
            acc0 = __builtin_amdgcn_mfma_f32_16x16x32_bf16(Ah[0][ks], bh, acc0, 0, 0, 0);
            acc0 = __builtin_amdgcn_mfma_f32_16x16x32_bf16(Al[0][ks], bh, acc0, 0, 0, 0);
            acc0 = __builtin_amdgcn_mfma_f32_16x16x32_bf16(Ah[0][ks], bl, acc0, 0, 0, 0);
            acc1 = __builtin_amdgcn_mfma_f32_16x16x32_bf16(Ah[1][ks], bh, acc1, 0, 0, 0);
            acc1 = __builtin_amdgcn_mfma_f32_16x16x32_bf16(Al[1][ks], bh, acc1, 0, 0, 0);
            acc1 = __builtin_amdgcn_mfma_f32_16x16x32_bf16(Ah[1][ks], bl, acc1, 0, 0, 0);
        }
        int col = nt * 16 + arow;
        float bias;
        if (col < 256) bias = bq[col];
        else if (col < 512) bias = bk[col - 256];
        else if (col < 768) bias = bv[col - 512];
        else bias = bs[col - 768];
        auto store_tile = [&](const floatx4& acc, int mrow0) {
#pragma unroll
            for (int r = 0; r < 4; ++r) {
                int node = mrow0 + kg * 4 + r;
                if (node < N) {
                    float val = acc[r] + bias;
                    if (col < 256)      q[(size_t)node * 256 + col] = f2h(val);
                    else if (col < 512) kv[(size_t)node * 512 + (col - 256)] = f2h(val);
                    else if (col < 768) kv[(size_t)node * 512 + 256 + (col - 512)] = f2h(val);
                    else                h[(size_t)node * HH + (col - 768)] = val;  // skip
                }
            }
        };
        store_tile(acc0, mbase);
        store_tile(acc1, mbase + 16);
    }
}

// ---------------------------------------------------------------------------
// Projection MFMA (layers 1,2): reads h, writes q/kv fp16 + skip into h.
// ---------------------------------------------------------------------------
__global__ void k_proj(float* __restrict__ h0, const unsigned short* __restrict__ panel,
                       const float* __restrict__ bq, const float* __restrict__ bk,
                       const float* __restrict__ bv, const float* __restrict__ bs,
                       unsigned short* __restrict__ qb0, unsigned short* __restrict__ kvb0,
                       int N, int brBase) {
    int slot = blockIdx.y;
    int br = brBase + slot;
    float* h = h0 + (size_t)br * N * HH;
    unsigned short* q = qb0 + (size_t)slot * N * 256;
    unsigned short* kv = kvb0 + (size_t)slot * N * 512;
    int t = threadIdx.x, lane = t & 63, wid = t >> 6;
    int arow = lane & 15, kg = lane >> 4;
    int mbase = blockIdx.x * 32;

    short8v Ah[2][2], Al[2][2];
#pragma unroll
    for (int mt = 0; mt < 2; ++mt) {
        int node = min(mbase + mt * 16 + arow, N - 1);
        const float* src = h + (size_t)node * HH + kg * 8;
#pragma unroll
        for (int ks = 0; ks < 2; ++ks) {
            const float4* pp = reinterpret_cast<const float4*>(src + ks * 32);
            float4 fa = pp[0], fb = pp[1];
            float v[8] = {fa.x, fa.y, fa.z, fa.w, fb.x, fb.y, fb.z, fb.w};
#pragma unroll
            for (int i = 0; i < 8; ++i) {
                unsigned short hi = f2bf(v[i]);
                Ah[mt][ks][i] = (short)hi;
                Al[mt][ks][i] = (short)f2bf(v[i] - bf2f(hi));
            }
        }
    }
    __syncthreads();   // all waves consumed h before skip overwrites it

    const unsigned short* ph = panel;
    const unsigned short* pl = panel + 832 * 64;
#pragma unroll
    for (int j = 0; j < 13; ++j) {
        int nt = wid * 13 + j;
        size_t boff = (size_t)(nt * 16 + arow) * 64 + kg * 8;
        floatx4 acc0 = {0.f, 0.f, 0.f, 0.f}, acc1 = {0.f, 0.f, 0.f, 0.f};
#pragma unroll
        for (int ks = 0; ks < 2; ++ks) {
            short8v bh = *reinterpret_cast<const short8v*>(ph + boff + ks * 32);
            short8v bl = *reinterpret_cast<const short8v*>(pl + boff + ks * 32);
            acc0 = __builtin_amdgcn_mfma_f32_16x16x32_bf16(Ah[0][ks], bh, acc0, 0, 0, 0);
            acc0 = __builtin_amdgcn_mfma_f32_16x16x32_bf16(Al[0][ks], bh, acc0, 0, 0, 0);
            acc0 = __builtin_amdgcn_mfma_f32_16x16x32_bf16(Ah[0][ks], bl, acc0, 0, 0, 0);
            acc1 = __builtin_amdgcn_mfma_f32_16x16x32_bf16(Ah[1][ks], bh, acc1, 0, 0, 0);
            acc1 = __builtin_amdgcn_mfma_f32_16x16x32_bf16(Al[1][ks], bh, acc1, 0, 0, 0);
            acc1 = __builtin_amdgcn_mfma_f32_16x16x32_bf16(Ah[1][ks], bl, acc1, 0, 0, 0);
        }
        int col = nt * 16 + arow;
        float bias;
        if (col < 256) bias = bq[col];
        else if (col < 512) bias = bk[col - 256];
        else if (col < 768) bias = bv[col - 512];
        else bias = bs[col - 768];
        auto store_tile = [&](const floatx4& acc, int mrow0) {
#pragma unroll
            for (int r = 0; r < 4; ++r) {
                int node = mrow0 + kg * 4 + r;
                if (node < N) {
                    float val = acc[r] + bias;
                    if (col < 256)      q[(size_t)node * 256 + col] = f2h(val);
                    else if (col < 512) kv[(size_t)node * 512 + (col - 256)] = f2h(val);
                    else if (col < 768) kv[(size_t)node * 512 + 256 + (col - 512)] = f2h(val);
                    else                h[(size_t)node * HH + (col - 768)] = val;  // skip
                }
            }
        };
        store_tile(acc0, mbase);
        store_tile(acc1, mbase + 16);
    }
}

// ---------------------------------------------------------------------------
// Attention aggregate. One wave per node; 32 lanes per edge (2 edges/pass),
// 8-edge chunks (4 K+V gathers in flight per half). fp16 q/k/v, v_dot2.
// Reads skip from h, overwrites h with relu(head_mean + skip).
// ---------------------------------------------------------------------------
__global__ void k_attn(const unsigned short* __restrict__ qb0,
                       const unsigned short* __restrict__ kvb0,
                       const int* __restrict__ indptr0, const int* __restrict__ srcs0,
                       float* __restrict__ h0, int N, int E, int brBase) {
    int slot = blockIdx.y;
    int br = brBase + slot;
    const unsigned short* qb = qb0 + (size_t)slot * N * 256;
    const unsigned short* kvb = kvb0 + (size_t)slot * N * 512;
    const int* indptr = indptr0 + (size_t)br * (N + 1);
    const int* srcs = srcs0 + (size_t)br * E;
    float* h = h0 + (size_t)br * N * HH;

    int t = threadIdx.x;
    int lane = t & 63;
    int half = lane >> 5;
    int il = lane & 31;
    int o = il & 7;
    int elemoff = (il >> 3) * 64 + o * 8;

    int wvg = blockIdx.x * 4 + (t >> 6);
    int nw = gridDim.x * 4;
    for (int n = wvg; n < N; n += nw) {
        int beg = indptr[n], end = indptr[n + 1];
        if (end == beg) {
            if (lane < 8) {
                float4 s0 = *reinterpret_cast<const float4*>(&h[(size_t)n * HH + o * 8]);
                float4 s1 = *reinterpret_cast<const float4*>(&h[(size_t)n * HH + o * 8 + 4]);
                s0.x = fmaxf(s0.x, 0.f); s0.y = fmaxf(s0.y, 0.f);
                s0.z = fmaxf(s0.z, 0.f); s0.w = fmaxf(s0.w, 0.f);
                s1.x = fmaxf(s1.x, 0.f); s1.y = fmaxf(s1.y, 0.f);
                s1.z = fmaxf(s1.z, 0.f); s1.w = fmaxf(s1.w, 0.f);
                *reinterpret_cast<float4*>(&h[(size_t)n * HH + o * 8]) = s0;
                *reinterpret_cast<float4*>(&h[(size_t)n * HH + o * 8 + 4]) = s1;
            }
            continue;
        }
        uint4 q4 = *reinterpret_cast<const uint4*>(qb + (size_t)n * 256 + elemoff);
        float m = -INFINITY, s = 0.f;
        float a0=0.f,a1=0.f,a2=0.f,a3=0.f,a4=0.f,a5=0.f,a6=0.f,a7=0.f;

        for (int e0 = beg; e0 < end; e0 += 8) {
            uint4 kk[4], vv[4];
            bool vd[4];
#pragma unroll
            for (int i = 0; i < 4; ++i) {
                int ei = e0 + 2 * i + half;
                bool ok = ei < end;
                vd[i] = ok;
                int src = srcs[ok ? ei : beg];
                const unsigned short* kb = kvb + ((size_t)src << 9) + elemoff;
                kk[i] = *reinterpret_cast<const uint4*>(kb);
                vv[i] = *reinterpret_cast<const uint4*>(kb + 256);
            }
            float lg[4];
#pragma unroll
            for (int i = 0; i < 4; ++i) {
                float d = dot8h(kk[i], q4);
                d += __shfl_xor(d, 1);
                d += __shfl_xor(d, 2);
                d += __shfl_xor(d, 4);
                lg[i] = vd[i] ? d * 0.125f : -INFINITY;
            }
            float cm = fmaxf(fmaxf(lg[0], lg[1]), fmaxf(lg[2], lg[3]));
            float mn = fmaxf(m, cm);
            float rs = (m == -INFINITY) ? 0.f : __expf(m - mn);
            s *= rs;
            a0*=rs; a1*=rs; a2*=rs; a3*=rs; a4*=rs; a5*=rs; a6*=rs; a7*=rs;
            m = mn;
#pragma unroll
            for (int i = 0; i < 4; ++i) {
                float p = vd[i] ? __expf(lg[i] - mn) : 0.f;
                s += p;
                float2 v01 = h2f(vv[i].x), v23 = h2f(vv[i].y);
                float2 v45 = h2f(vv[i].z), v67 = h2f(vv[i].w);
                a0 += p * v01.x; a1 += p * v01.y; a2 += p * v23.x; a3 += p * v23.y;
                a4 += p * v45.x; a5 += p * v45.y; a6 += p * v67.x; a7 += p * v67.y;
            }
        }
        // merge the two independent online-softmax halves
        float mo = __shfl_xor(m, 32);
        float mt2 = fmaxf(m, mo);
        float myscale = (m == -INFINITY) ? 0.f : __expf(m - mt2);
        float ss = s * myscale;
        float st = ss + __shfl_xor(ss, 32);
        float inv = 1.f / st;
        a0 *= myscale; a0 += __shfl_xor(a0, 32);
        a1 *= myscale; a1 += __shfl_xor(a1, 32);
        a2 *= myscale; a2 += __shfl_xor(a2, 32);
        a3 *= myscale; a3 += __shfl_xor(a3, 32);
        a4 *= myscale; a4 += __shfl_xor(a4, 32);
        a5 *= myscale; a5 += __shfl_xor(a5, 32);
        a6 *= myscale; a6 += __shfl_xor(a6, 32);
        a7 *= myscale; a7 += __shfl_xor(a7, 32);
        a0 *= inv; a1 *= inv; a2 *= inv; a3 *= inv;
        a4 *= inv; a5 *= inv; a6 *= inv; a7 *= inv;
        // head mean
        a0 += __shfl_xor(a0, 8);  a0 += __shfl_xor(a0, 16);
        a1 += __shfl_xor(a1, 8);  a1 += __shfl_xor(a1, 16);
        a2 += __shfl_xor(a2, 8);  a2 += __shfl_xor(a2, 16);
        a3 += __shfl_xor(a3, 8);  a3 += __shfl_xor(a3, 16);
        a4 += __shfl_xor(a4, 8);  a4 += __shfl_xor(a4, 16);
        a5 += __shfl_xor(a5, 8);  a5 += __shfl_xor(a5, 16);
        a6 += __shfl_xor(a6, 8);  a6 += __shfl_xor(a6, 16);
        a7 += __shfl_xor(a7, 8);  a7 += __shfl_xor(a7, 16);
        if (lane < 8) {
            float4 s0 = *reinterpret_cast<const float4*>(&h[(size_t)n * HH + o * 8]);
            float4 s1 = *reinterpret_cast<const float4*>(&h[(size_t)n * HH + o * 8 + 4]);
            float4 r0, r1;
            r0.x = fmaxf(0.25f * a0 + s0.x, 0.f);
            r0.y = fmaxf(0.25f * a1 + s0.y, 0.f);
            r0.z = fmaxf(0.25f * a2 + s0.z, 0.f);
            r0.w = fmaxf(0.25f * a3 + s0.w, 0.f);
            r1.x = fmaxf(0.25f * a4 + s1.x, 0.f);
            r1.y = fmaxf(0.25f * a5 + s1.y, 0.f);
            r1.z = fmaxf(0.25f * a6 + s1.z, 0.f);
            r1.w = fmaxf(0.25f * a7 + s1.w, 0.f);
            *reinterpret_cast<float4*>(&h[(size_t)n * HH + o * 8]) = r0;
            *reinterpret_cast<float4*>(&h[(size_t)n * HH + o * 8 + 4]) = r1;
        }
    }
}

// ---------------------------------------------------------------------------
// Mean pool (batch sorted, run-length accumulate), both branches
// ---------------------------------------------------------------------------
__global__ void k_pool(const float* __restrict__ h0, const int* __restrict__ batA,
                       const int* __restrict__ batB,
                       float* __restrict__ pooled, float* __restrict__ cnt, int N) {
    int br = blockIdx.y;
    const float* h = h0 + (size_t)br * N * HH;
    const int* batch = br ? batB : batA;
    float* pb = pooled + (size_t)br * GG * HH;
    float* cb = cnt + (size_t)br * GG;
    int j = threadIdx.x;
    int n0 = blockIdx.x * 32;
    int n1 = min(n0 + 32, N);
    if (n0 >= N) return;
    float acc = 0.f;
    int c = 0;
    int gcur = batch[n0];
    for (int n = n0; n < n1; ++n) {
        int g = batch[n];
        if (g != gcur) {
            atomicAdd(&pb[gcur * HH + j], acc);
            if (j == 0) atomicAdd(&cb[gcur], (float)c);
            acc = 0.f; c = 0; gcur = g;
        }
        acc += h[(size_t)n * HH + j];
        ++c;
    }
    atomicAdd(&pb[gcur * HH + j], acc);
    if (j == 0) atomicAdd(&cb[gcur], (float)c);
}

// ---------------------------------------------------------------------------
// Head: pool finalize, MHA over seq=2, mean, classifier. Block per graph.
// ---------------------------------------------------------------------------
__global__ void k_head(const float* __restrict__ pooled, const float* __restrict__ cnt,
                       const float* __restrict__ in_w, const float* __restrict__ in_b,
                       const float* __restrict__ out_w, const float* __restrict__ out_b,
                       const float* __restrict__ Wc1, const float* __restrict__ bc1,
                       const float* __restrict__ Wc2, const float* __restrict__ bc2,
                       float* __restrict__ out) {
    int g = blockIdx.x;
    int t = threadIdx.x;
    __shared__ float xs[2][HH];
    __shared__ float qkvs[2][3 * HH];
    __shared__ float sc[2][2][NHEADS];
    __shared__ float os[2][HH];
    __shared__ float xf[HH];
    __shared__ float r1[HH / 2];

    for (int s = 0; s < 2; ++s) {
        float c = fmaxf(cnt[s * GG + g], 1.f);
        xs[s][t] = pooled[(size_t)s * GG * HH + g * HH + t] / c;
    }
    __syncthreads();
    for (int idx = t; idx < 2 * 192; idx += 64) {
        int s = idx / 192, i = idx % 192;
        float a = in_b[i];
#pragma unroll 8
        for (int j = 0; j < HH; ++j) a += xs[s][j] * in_w[i * HH + j];
        qkvs[s][i] = a;
    }
    __syncthreads();
    if (t < 16) {
        int s1 = t >> 3, s2 = (t >> 2) & 1, hh = t & 3;
        float a = 0.f;
#pragma unroll
        for (int d = 0; d < 16; ++d) a += qkvs[s1][hh * 16 + d] * qkvs[s2][HH + hh * 16 + d];
        sc[s1][s2][hh] = a * 0.25f;
    }
    __syncthreads();
    {
        int hh = t >> 4;
        for (int s1 = 0; s1 < 2; ++s1) {
            float a0 = sc[s1][0][hh], a1 = sc[s1][1][hh];
            float mx = fmaxf(a0, a1);
            float e0 = __expf(a0 - mx), e1 = __expf(a1 - mx);
            float inv = 1.f / (e0 + e1);
            os[s1][t] = (e0 * inv) * qkvs[0][2 * HH + t] + (e1 * inv) * qkvs[1][2 * HH + t];
        }
    }
    __syncthreads();
    {
        float acc0 = 0.f, acc1 = 0.f;
#pragma unroll 8
        for (int k2 = 0; k2 < HH; ++k2) {
            float w = out_w[t * HH + k2];
            acc0 += os[0][k2] * w;
            acc1 += os[1][k2] * w;
        }
        xf[t] = 0.5f * (acc0 + acc1) + out_b[t];
    }
    __syncthreads();
    if (t < 32) {
        float a = bc1[t];
#pragma unroll 8
        for (int j = 0; j < HH; ++j) a += xf[j] * Wc1[j * 32 + t];
        r1[t] = fmaxf(a, 0.f);
    }
    __syncthreads();
    if (t < CCLS) {
        float a = bc2[t];
#pragma unroll
        for (int j2 = 0; j2 < 32; ++j2) a += r1[j2] * Wc2[j2 * CCLS + t];
        out[g * CCLS + t] = a;
    }
}

// ---------------------------------------------------------------------------
extern "C" void kernel_launch(void* const* d_in, const int* in_sizes, int n_in,
                              void* d_out, int out_size, void* d_ws, size_t ws_size,
                              hipStream_t stream) {
    const float* x1    = (const float*)d_in[0];
    const float* x2    = (const float*)d_in[1];
    const int*   ei1   = (const int*)d_in[2];
    const int*   ei2   = (const int*)d_in[3];
    const int*   bat1  = (const int*)d_in[4];
    const int*   bat2  = (const int*)d_in[5];
    const float* W_emb = (const float*)d_in[6];
    const float* b_emb = (const float*)d_in[7];
    const float* temb  = (const float*)d_in[8];
    const float* Wq    = (const float*)d_in[9];
    const float* bq    = (const float*)d_in[10];
    const float* Wk    = (const float*)d_in[11];
    const float* bk    = (const float*)d_in[12];
    const float* Wv    = (const float*)d_in[13];
    const float* bv    = (const float*)d_in[14];
    const float* Ws    = (const float*)d_in[15];
    const float* bs    = (const float*)d_in[16];
    const float* miw   = (const float*)d_in[17];
    const float* mib   = (const float*)d_in[18];
    const float* mow   = (const float*)d_in[19];
    const float* mob   = (const float*)d_in[20];
    const float* Wc1   = (const float*)d_in[21];
    const float* bc1   = (const float*)d_in[22];
    const float* Wc2   = (const float*)d_in[23];
    const float* bc2   = (const float*)d_in[24];

    const int N = in_sizes[4];        // 20000
    const int E = in_sizes[2] / 2;    // 320000

    auto al = [](size_t b) { return (b + 255) & ~(size_t)255; };
    auto need = [&](int NBs) -> size_t {
        size_t s = 0;
        s += al((size_t)2 * N * HH * 4);                 // h
        s += al((size_t)NBs * N * 256 * 2);              // qb
        s += al((size_t)NBs * N * 512 * 2);              // kvb
        s += al((size_t)(2 * GG * HH * 4 + 2 * GG * 4 + (size_t)2 * N * 4) + 512); // zero region
        s += al((size_t)2 * (N + 1) * 4);                // indptr
        s += al((size_t)2 * N * 4);                      // cursor
        s += al((size_t)2 * E * 4);                      // srcs
        s += al((size_t)2 * 1024 * 4) * 2;               // btot, btote
        s += al((size_t)3 * 2 * 832 * 64 * 2);           // panel
        s += al((size_t)2 * 64 * 256 * 2);               // panelE
        return s;
    };
    const bool dual = ws_size >= need(2);
    const int NBs = dual ? 2 : 1;

    char* p = (char*)d_ws;
    auto carve = [&](size_t bytes) {
        void* r = (void*)p;
        p += al(bytes);
        return r;
    };
    float*          h      = (float*)carve((size_t)2 * N * HH * 4);
    unsigned short* qb     = (unsigned short*)carve((size_t)NBs * N * 256 * 2);
    unsigned short* kvb    = (unsigned short*)carve((size_t)NBs * N * 512 * 2);
    // zero region: pooled | cnt | counts (single memset)
    size_t zbytes = (size_t)2 * GG * HH * 4 + (size_t)2 * GG * 4 + (size_t)2 * N * 4 + 512;
    char*  zbase  = (char*)carve(zbytes);
    float* pooled = (float*)zbase;
    float* cnt    = (float*)(zbase + al((size_t)2 * GG * HH * 4));
    int*   counts = (int*)(zbase + al((size_t)2 * GG * HH * 4) + al((size_t)2 * GG * 4));
    int*            indptr = (int*)carve((size_t)2 * (N + 1) * 4);
    int*            cursor = (int*)carve((size_t)2 * N * 4);
    int*            srcs   = (int*)carve((size_t)2 * E * 4);
    int*            btot   = (int*)carve((size_t)2 * 1024 * 4);
    int*            btote  = (int*)carve((size_t)2 * 1024 * 4);
    unsigned short* panel  = (unsigned short*)carve((size_t)3 * 2 * 832 * 64 * 2);
    unsigned short* panelE = (unsigned short*)carve((size_t)2 * 64 * 256 * 2);

    hipMemsetAsync(zbase, 0, zbytes, stream);

    const int packTot = 3 * 832 * 64 + 64 * 256;
    k_pack<<<(packTot + 255) / 256, 256, 0, stream>>>(Wq, Wk, Wv, Ws, W_emb, panel, panelE);

    const int nb = (N + 1023) / 1024;             // 20
    k_hist<<<dim3((E + 255) / 256, 2), 256, 0, stream>>>(ei1, ei2, E, counts, N);
    k_scan_part<<<dim3(nb, 2), 1024, 0, stream>>>(counts, N, indptr, btot);
    k_scan_mid<<<dim3(1, 2), 1024, 0, stream>>>(nb, btot, btote);
    k_scan_fix<<<dim3(nb, 2), 1024, 0, stream>>>(N, nb, indptr, cursor, btot, btote);
    k_scatter<<<dim3((E + 255) / 256, 2), 256, 0, stream>>>(ei1, ei2, E, cursor, srcs, N);

    const int projGX = (N + 31) / 32;
    const int attnGX = min((N + 3) / 4, 2048);

    for (int pass = 0; pass < (dual ? 1 : 2); ++pass) {
        int brBase = dual ? 0 : pass;
        k_embed_proj<<<dim3(projGX, NBs), 256, 0, stream>>>(
            x1, x2, panelE, b_emb, temb, panel,
            bq, bk, bv, bs, h, qb, kvb, N, brBase);
        k_attn<<<dim3(attnGX, NBs), 256, 0, stream>>>(qb, kvb, indptr, srcs, h, N, E, brBase);
        for (int l = 1; l < LLAY; ++l) {
            k_proj<<<dim3(projGX, NBs), 256, 0, stream>>>(
                h, panel + (size_t)l * 2 * 832 * 64,
                bq + (size_t)l * 256, bk + (size_t)l * 256, bv + (size_t)l * 256, bs + (size_t)l * 64,
                qb, kvb, N, brBase);
            k_attn<<<dim3(attnGX, NBs), 256, 0, stream>>>(qb, kvb, indptr, srcs, h, N, E, brBase);
        }
    }

    k_pool<<<dim3((N + 31) / 32, 2), 64, 0, stream>>>(h, bat1, bat2, pooled, cnt, N);

    k_head<<<GG, 64, 0, stream>>>(pooled, cnt, miw, mib, mow, mob, Wc1, bc1, Wc2, bc2,
                                  (float*)d_out);
}

// Round 9
// 588.138 us; speedup vs baseline: 1.1107x; 1.0232x over previous
//
#include <hip/hip_runtime.h>
#include <math.h>

#define FF   256
#define HH   64
#define NHEADS 4
#define LLAY 3
#define GG   64
#define CCLS 10
#define OPAD 840    // out16 row stride (832 + 8 pad)

typedef __attribute__((ext_vector_type(8))) short short8v;
typedef __attribute__((ext_vector_type(4))) float floatx4;
typedef __attribute__((ext_vector_type(2))) _Float16 h2v;

#if defined(__has_builtin)
#if __has_builtin(__builtin_amdgcn_fdot2)
#define HAS_FDOT2 1
#endif
#endif

__device__ __forceinline__ unsigned short f2bf(float f) {
    unsigned int u = __float_as_uint(f);
    unsigned int r = (u + 0x7fffu + ((u >> 16) & 1u)) >> 16;   // RNE
    return (unsigned short)r;
}
__device__ __forceinline__ float bf2f(unsigned short h) {
    return __uint_as_float((unsigned int)h << 16);
}
__device__ __forceinline__ unsigned short f2h(float f) {
    _Float16 h = (_Float16)f;
    return __builtin_bit_cast(unsigned short, h);
}
__device__ __forceinline__ float2 h2f(unsigned int u) {
    h2v h = __builtin_bit_cast(h2v, u);
    return make_float2((float)h.x, (float)h.y);
}
__device__ __forceinline__ float dot8h(uint4 k, uint4 q) {
#ifdef HAS_FDOT2
    float d = 0.f;
    d = __builtin_amdgcn_fdot2(__builtin_bit_cast(h2v, k.x), __builtin_bit_cast(h2v, q.x), d, false);
    d = __builtin_amdgcn_fdot2(__builtin_bit_cast(h2v, k.y), __builtin_bit_cast(h2v, q.y), d, false);
    d = __builtin_amdgcn_fdot2(__builtin_bit_cast(h2v, k.z), __builtin_bit_cast(h2v, q.z), d, false);
    d = __builtin_amdgcn_fdot2(__builtin_bit_cast(h2v, k.w), __builtin_bit_cast(h2v, q.w), d, false);
    return d;
#else
    float2 k0 = h2f(k.x), k1 = h2f(k.y), k2 = h2f(k.z), k3 = h2f(k.w);
    float2 q0 = h2f(q.x), q1 = h2f(q.y), q2 = h2f(q.z), q3 = h2f(q.w);
    return k0.x*q0.x + k0.y*q0.y + k1.x*q1.x + k1.y*q1.y +
           k2.x*q2.x + k2.y*q2.y + k3.x*q3.x + k3.y*q3.y;
#endif
}

// ---------------------------------------------------------------------------
// Weight packing (bf16 hi/lo panels), proj + embed in one kernel.
// ---------------------------------------------------------------------------
__global__ void k_pack(const float* __restrict__ Wq, const float* __restrict__ Wk,
                       const float* __restrict__ Wv, const float* __restrict__ Ws,
                       const float* __restrict__ We,
                       unsigned short* __restrict__ panel, unsigned short* __restrict__ pE) {
    int idx = blockIdx.x * 256 + threadIdx.x;
    if (idx < 3 * 832 * 64) {
        int l = idx / (832 * 64);
        int rem = idx % (832 * 64);
        int c = rem / 64, k = rem % 64;
        float v;
        if (c < 256)      v = Wq[((size_t)l * 64 + k) * 256 + c];
        else if (c < 512) v = Wk[((size_t)l * 64 + k) * 256 + (c - 256)];
        else if (c < 768) v = Wv[((size_t)l * 64 + k) * 256 + (c - 512)];
        else              v = Ws[((size_t)l * 64 + k) * 64 + (c - 768)];
        unsigned short hi = f2bf(v);
        unsigned short lo = f2bf(v - bf2f(hi));
        panel[((size_t)l * 2 + 0) * 832 * 64 + rem] = hi;
        panel[((size_t)l * 2 + 1) * 832 * 64 + rem] = lo;
    } else {
        int e = idx - 3 * 832 * 64;
        if (e >= 64 * 256) return;
        int c = e / 256, k = e % 256;
        float v = We[(size_t)k * 64 + c];
        unsigned short hi = f2bf(v);
        unsigned short lo = f2bf(v - bf2f(hi));
        pE[e] = hi;
        pE[64 * 256 + e] = lo;
    }
}

// ---------------------------------------------------------------------------
// dst-CSR build, both branches (br = blockIdx.y)
// ---------------------------------------------------------------------------
__global__ void k_hist(const int* __restrict__ eiA, const int* __restrict__ eiB, int E,
                       int* __restrict__ counts0, int N) {
    int br = blockIdx.y;
    const int* dst = (br ? eiB : eiA) + E;
    int* c = counts0 + (size_t)br * N;
    int i = blockIdx.x * blockDim.x + threadIdx.x;
    if (i < E) atomicAdd(&c[dst[i]], 1);
}

__global__ void k_scan_part(const int* __restrict__ counts0, int N,
                            int* __restrict__ ip0, int* __restrict__ btot) {
    int br = blockIdx.y, b = blockIdx.x, t = threadIdx.x;
    const int* counts = counts0 + (size_t)br * N;
    int* ip = ip0 + (size_t)br * (N + 1);
    __shared__ int sd[1024];
    int i = b * 1024 + t;
    int v = (i < N) ? counts[i] : 0;
    sd[t] = v;
    __syncthreads();
    for (int off = 1; off < 1024; off <<= 1) {
        int x = (t >= off) ? sd[t - off] : 0;
        __syncthreads();
        sd[t] += x;
        __syncthreads();
    }
    if (i < N) ip[i] = sd[t] - v;
    if (t == 1023) btot[br * 1024 + b] = sd[1023];
}

__global__ void k_scan_mid(int nb, const int* __restrict__ btot, int* __restrict__ btote) {
    int br = blockIdx.y, t = threadIdx.x;
    __shared__ int sd[1024];
    int v = (t < nb) ? btot[br * 1024 + t] : 0;
    sd[t] = v;
    __syncthreads();
    for (int off = 1; off < 1024; off <<= 1) {
        int x = (t >= off) ? sd[t - off] : 0;
        __syncthreads();
        sd[t] += x;
        __syncthreads();
    }
    if (t < nb) btote[br * 1024 + t] = sd[t] - v;
}

__global__ void k_scan_fix(int N, int nb, int* __restrict__ ip0, int* __restrict__ cursor0,
                           const int* __restrict__ btot, const int* __restrict__ btote) {
    int br = blockIdx.y, b = blockIdx.x, t = threadIdx.x;
    int* ip = ip0 + (size_t)br * (N + 1);
    int* cursor = cursor0 + (size_t)br * N;
    int soff = btote[br * 1024 + b];
    if (t == 0 && b == nb - 1) ip[N] = soff + btot[br * 1024 + b];
    int i = b * 1024 + t;
    if (i < N) {
        int val = ip[i] + soff;
        ip[i] = val;
        cursor[i] = val;
    }
}

__global__ void k_scatter(const int* __restrict__ eiA, const int* __restrict__ eiB, int E,
                          int* __restrict__ cursor0, int* __restrict__ srcs0, int N) {
    int br = blockIdx.y;
    const int* ei = br ? eiB : eiA;
    int* cursor = cursor0 + (size_t)br * N;
    int* srcs = srcs0 + (size_t)br * E;
    int i = blockIdx.x * blockDim.x + threadIdx.x;
    if (i < E) {
        int p = atomicAdd(&cursor[ei[E + i]], 1);
        srcs[p] = ei[i];
    }
}

// ---------------------------------------------------------------------------
// Shared device helpers for proj-style kernels
// ---------------------------------------------------------------------------
__device__ __forceinline__ void proj_mfma_loop(
        const unsigned short* __restrict__ panel,
        const float* __restrict__ bq, const float* __restrict__ bk,
        const float* __restrict__ bv, const float* __restrict__ bs,
        const short8v Ah[2][2], const short8v Al[2][2],
        unsigned short (*out16)[OPAD], float (*skl)[68],
        int wid, int arow, int kg) {
    const unsigned short* ph = panel;
    const unsigned short* pl = panel + 832 * 64;
#pragma unroll
    for (int j = 0; j < 13; ++j) {
        int nt = wid * 13 + j;
        size_t boff = (size_t)(nt * 16 + arow) * 64 + kg * 8;
        floatx4 acc0 = {0.f, 0.f, 0.f, 0.f}, acc1 = {0.f, 0.f, 0.f, 0.f};
#pragma unroll
        for (int ks = 0; ks < 2; ++ks) {
            short8v bh = *reinterpret_cast<const short8v*>(ph + boff + ks * 32);
            short8v bl = *reinterpret_cast<const short8v*>(pl + boff + ks * 32);
            acc0 = __builtin_amdgcn_mfma_f32_16x16x32_bf16(Ah[0][ks], bh, acc0, 0, 0, 0);
            acc0 = __builtin_amdgcn_mfma_f32_16x16x32_bf16(Al[0][ks], bh, acc0, 0, 0, 0);
            acc0 = __builtin_amdgcn_mfma_f32_16x16x32_bf16(Ah[0][ks], bl, acc0, 0, 0, 0);
            acc1 = __builtin_amdgcn_mfma_f32_16x16x32_bf16(Ah[1][ks], bh, acc1, 0, 0, 0);
            acc1 = __builtin_amdgcn_mfma_f32_16x16x32_bf16(Al[1][ks], bh, acc1, 0, 0, 0);
            acc1 = __builtin_amdgcn_mfma_f32_16x16x32_bf16(Ah[1][ks], bl, acc1, 0, 0, 0);
        }
        int col = nt * 16 + arow;
        float bias;
        if (col < 256) bias = bq[col];
        else if (col < 512) bias = bk[col - 256];
        else if (col < 768) bias = bv[col - 512];
        else bias = bs[col - 768];
#pragma unroll
        for (int r = 0; r < 4; ++r) {
            float v0 = acc0[r] + bias;
            float v1 = acc1[r] + bias;
            int nl0 = kg * 4 + r, nl1 = 16 + kg * 4 + r;
            if (col < 768) {
                out16[nl0][col] = f2h(v0);
                out16[nl1][col] = f2h(v1);
            } else {
                skl[nl0][col - 768] = v0;
                skl[nl1][col - 768] = v1;
            }
        }
    }
}

__device__ __forceinline__ void proj_copy_out(
        const unsigned short (*out16)[OPAD], const float (*skl)[68],
        unsigned short* __restrict__ q, unsigned short* __restrict__ kv,
        float* __restrict__ h, int mbase, int N, int t) {
    // q: 32 nodes x 256 u16 = 1024 uint4
    for (int c = t; c < 1024; c += 256) {
        int nl = c >> 5, off = (c & 31) * 8;
        int node = mbase + nl;
        if (node < N)
            *reinterpret_cast<uint4*>(q + (size_t)node * 256 + off) =
                *reinterpret_cast<const uint4*>(&out16[nl][off]);
    }
    // kv: 32 nodes x 512 u16 = 2048 uint4
    for (int c = t; c < 2048; c += 256) {
        int nl = c >> 6, off = (c & 63) * 8;
        int node = mbase + nl;
        if (node < N)
            *reinterpret_cast<uint4*>(kv + (size_t)node * 512 + off) =
                *reinterpret_cast<const uint4*>(&out16[nl][256 + off]);
    }
    // skip -> h: 32 nodes x 64 f32 = 512 float4
    for (int c = t; c < 512; c += 256) {
        int nl = c >> 4, off = (c & 15) * 4;
        int node = mbase + nl;
        if (node < N)
            *reinterpret_cast<float4*>(h + (size_t)node * HH + off) =
                *reinterpret_cast<const float4*>(&skl[nl][off]);
    }
}

// ---------------------------------------------------------------------------
// Fused embed + layer-0 projection. 32 nodes/block. LDS-staged coalesced out.
// ---------------------------------------------------------------------------
__global__ void k_embed_proj(const float* __restrict__ xa, const float* __restrict__ xb,
                             const unsigned short* __restrict__ pE,
                             const float* __restrict__ bemb, const float* __restrict__ temb,
                             const unsigned short* __restrict__ panel,
                             const float* __restrict__ bq, const float* __restrict__ bk,
                             const float* __restrict__ bv, const float* __restrict__ bs,
                             float* __restrict__ h0, unsigned short* __restrict__ qb0,
                             unsigned short* __restrict__ kvb0, int N, int brBase) {
    int slot = blockIdx.y;
    int br = brBase + slot;
    const float* x = br ? xb : xa;
    float* h = h0 + (size_t)br * N * HH;
    unsigned short* q = qb0 + (size_t)slot * N * 256;
    unsigned short* kv = kvb0 + (size_t)slot * N * 512;

    __shared__ float hs[32][68];                 // embed result, reused for skip
    __shared__ unsigned short out16[32][OPAD];   // q|k|v staging
    int t = threadIdx.x, lane = t & 63, wid = t >> 6;
    int arow = lane & 15, kg = lane >> 4;
    int mbase = blockIdx.x * 32;

    // ---- embed (MFMA, bf16x3 split) -> hs ----
    {
        int n0 = min(mbase + arow, N - 1);
        int n1 = min(mbase + 16 + arow, N - 1);
        const float* x0 = x + (size_t)n0 * FF + kg * 8;
        const float* x1 = x + (size_t)n1 * FF + kg * 8;
        const unsigned short* bh = pE + (size_t)(wid * 16 + arow) * FF + kg * 8;
        const unsigned short* bl = bh + 64 * FF;
        floatx4 acc0 = {0.f, 0.f, 0.f, 0.f}, acc1 = {0.f, 0.f, 0.f, 0.f};
#pragma unroll
        for (int ks = 0; ks < 8; ++ks) {
            const float4* p0 = reinterpret_cast<const float4*>(x0 + ks * 32);
            float4 f00 = p0[0], f01 = p0[1];
            const float4* p1 = reinterpret_cast<const float4*>(x1 + ks * 32);
            float4 f10 = p1[0], f11 = p1[1];
            float v0[8] = {f00.x, f00.y, f00.z, f00.w, f01.x, f01.y, f01.z, f01.w};
            float v1[8] = {f10.x, f10.y, f10.z, f10.w, f11.x, f11.y, f11.z, f11.w};
            short8v a0h, a0l, a1h, a1l;
#pragma unroll
            for (int i = 0; i < 8; ++i) {
                unsigned short h0v = f2bf(v0[i]);
                a0h[i] = (short)h0v; a0l[i] = (short)f2bf(v0[i] - bf2f(h0v));
                unsigned short h1v = f2bf(v1[i]);
                a1h[i] = (short)h1v; a1l[i] = (short)f2bf(v1[i] - bf2f(h1v));
            }
            short8v bhv = *reinterpret_cast<const short8v*>(bh + ks * 32);
            short8v blv = *reinterpret_cast<const short8v*>(bl + ks * 32);
            acc0 = __builtin_amdgcn_mfma_f32_16x16x32_bf16(a0h, bhv, acc0, 0, 0, 0);
            acc0 = __builtin_amdgcn_mfma_f32_16x16x32_bf16(a0l, bhv, acc0, 0, 0, 0);
            acc0 = __builtin_amdgcn_mfma_f32_16x16x32_bf16(a0h, blv, acc0, 0, 0, 0);
            acc1 = __builtin_amdgcn_mfma_f32_16x16x32_bf16(a1h, bhv, acc1, 0, 0, 0);
            acc1 = __builtin_amdgcn_mfma_f32_16x16x32_bf16(a1l, bhv, acc1, 0, 0, 0);
            acc1 = __builtin_amdgcn_mfma_f32_16x16x32_bf16(a1h, blv, acc1, 0, 0, 0);
        }
        int col = wid * 16 + arow;
        float bias = bemb[col] + temb[(size_t)br * HH + col];
#pragma unroll
        for (int r = 0; r < 4; ++r) {
            hs[kg * 4 + r][col] = acc0[r] + bias;
            hs[16 + kg * 4 + r][col] = acc1[r] + bias;
        }
    }
    __syncthreads();

    // ---- A fragments from hs ----
    short8v Ah[2][2], Al[2][2];
#pragma unroll
    for (int mt = 0; mt < 2; ++mt) {
#pragma unroll
        for (int ks = 0; ks < 2; ++ks) {
            const float4* pp = reinterpret_cast<const float4*>(&hs[mt * 16 + arow][ks * 32 + kg * 8]);
            float4 fa = pp[0], fb = pp[1];
            float v[8] = {fa.x, fa.y, fa.z, fa.w, fb.x, fb.y, fb.z, fb.w};
#pragma unroll
            for (int i = 0; i < 8; ++i) {
                unsigned short hi = f2bf(v[i]);
                Ah[mt][ks][i] = (short)hi;
                Al[mt][ks][i] = (short)f2bf(v[i] - bf2f(hi));
            }
        }
    }
    __syncthreads();   // hs free for skip staging

    proj_mfma_loop(panel, bq, bk, bv, bs, Ah, Al, out16, hs, wid, arow, kg);
    __syncthreads();
    proj_copy_out(out16, hs, q, kv, h, mbase, N, t);
}

// ---------------------------------------------------------------------------
// Projection (layers 1,2): reads h, LDS-staged coalesced output.
// ---------------------------------------------------------------------------
__global__ void k_proj(float* __restrict__ h0, const unsigned short* __restrict__ panel,
                       const float* __restrict__ bq, const float* __restrict__ bk,
                       const float* __restrict__ bv, const float* __restrict__ bs,
                       unsigned short* __restrict__ qb0, unsigned short* __restrict__ kvb0,
                       int N, int brBase) {
    int slot = blockIdx.y;
    int br = brBase + slot;
    float* h = h0 + (size_t)br * N * HH;
    unsigned short* q = qb0 + (size_t)slot * N * 256;
    unsigned short* kv = kvb0 + (size_t)slot * N * 512;

    __shared__ float skl[32][68];
    __shared__ unsigned short out16[32][OPAD];
    int t = threadIdx.x, lane = t & 63, wid = t >> 6;
    int arow = lane & 15, kg = lane >> 4;
    int mbase = blockIdx.x * 32;

    short8v Ah[2][2], Al[2][2];
#pragma unroll
    for (int mt = 0; mt < 2; ++mt) {
        int node = min(mbase + mt * 16 + arow, N - 1);
        const float* src = h + (size_t)node * HH + kg * 8;
#pragma unroll
        for (int ks = 0; ks < 2; ++ks) {
            const float4* pp = reinterpret_cast<const float4*>(src + ks * 32);
            float4 fa = pp[0], fb = pp[1];
            float v[8] = {fa.x, fa.y, fa.z, fa.w, fb.x, fb.y, fb.z, fb.w};
#pragma unroll
            for (int i = 0; i < 8; ++i) {
                unsigned short hi = f2bf(v[i]);
                Ah[mt][ks][i] = (short)hi;
                Al[mt][ks][i] = (short)f2bf(v[i] - bf2f(hi));
            }
        }
    }

    proj_mfma_loop(panel, bq, bk, bv, bs, Ah, Al, out16, skl, wid, arow, kg);
    __syncthreads();   // also orders h reads (A-frags) before h writes below
    proj_copy_out(out16, skl, q, kv, h, mbase, N, t);
}

// ---------------------------------------------------------------------------
// Attention aggregate. One wave per node; 32 lanes per edge (2 edges/pass),
// 8-edge chunks. fp16 q/k/v, v_dot2. h updated in place.
// ---------------------------------------------------------------------------
__global__ void k_attn(const unsigned short* __restrict__ qb0,
                       const unsigned short* __restrict__ kvb0,
                       const int* __restrict__ indptr0, const int* __restrict__ srcs0,
                       float* __restrict__ h0, int N, int E, int brBase) {
    int slot = blockIdx.y;
    int br = brBase + slot;
    const unsigned short* qb = qb0 + (size_t)slot * N * 256;
    const unsigned short* kvb = kvb0 + (size_t)slot * N * 512;
    const int* indptr = indptr0 + (size_t)br * (N + 1);
    const int* srcs = srcs0 + (size_t)br * E;
    float* h = h0 + (size_t)br * N * HH;

    int t = threadIdx.x;
    int lane = t & 63;
    int half = lane >> 5;
    int il = lane & 31;
    int o = il & 7;
    int elemoff = (il >> 3) * 64 + o * 8;

    int wvg = blockIdx.x * 4 + (t >> 6);
    int nw = gridDim.x * 4;
    for (int n = wvg; n < N; n += nw) {
        int beg = indptr[n], end = indptr[n + 1];
        if (end == beg) {
            if (lane < 8) {
                float4 s0 = *reinterpret_cast<const float4*>(&h[(size_t)n * HH + o * 8]);
                float4 s1 = *reinterpret_cast<const float4*>(&h[(size_t)n * HH + o * 8 + 4]);
                s0.x = fmaxf(s0.x, 0.f); s0.y = fmaxf(s0.y, 0.f);
                s0.z = fmaxf(s0.z, 0.f); s0.w = fmaxf(s0.w, 0.f);
                s1.x = fmaxf(s1.x, 0.f); s1.y = fmaxf(s1.y, 0.f);
                s1.z = fmaxf(s1.z, 0.f); s1.w = fmaxf(s1.w, 0.f);
                *reinterpret_cast<float4*>(&h[(size_t)n * HH + o * 8]) = s0;
                *reinterpret_cast<float4*>(&h[(size_t)n * HH + o * 8 + 4]) = s1;
            }
            continue;
        }
        uint4 q4 = *reinterpret_cast<const uint4*>(qb + (size_t)n * 256 + elemoff);
        float m = -INFINITY, s = 0.f;
        float a0=0.f,a1=0.f,a2=0.f,a3=0.f,a4=0.f,a5=0.f,a6=0.f,a7=0.f;

        for (int e0 = beg; e0 < end; e0 += 8) {
            uint4 kk[4], vv[4];
            bool vd[4];
#pragma unroll
            for (int i = 0; i < 4; ++i) {
                int ei = e0 + 2 * i + half;
                bool ok = ei < end;
                vd[i] = ok;
                int src = srcs[ok ? ei : beg];
                const unsigned short* kb = kvb + ((size_t)src << 9) + elemoff;
                kk[i] = *reinterpret_cast<const uint4*>(kb);
                vv[i] = *reinterpret_cast<const uint4*>(kb + 256);
            }
            float lg[4];
#pragma unroll
            for (int i = 0; i < 4; ++i) {
                float d = dot8h(kk[i], q4);
                d += __shfl_xor(d, 1);
                d += __shfl_xor(d, 2);
                d += __shfl_xor(d, 4);
                lg[i] = vd[i] ? d * 0.125f : -INFINITY;
            }
            float cm = fmaxf(fmaxf(lg[0], lg[1]), fmaxf(lg[2], lg[3]));
            float mn = fmaxf(m, cm);
            float rs = (m == -INFINITY) ? 0.f : __expf(m - mn);
            s *= rs;
            a0*=rs; a1*=rs; a2*=rs; a3*=rs; a4*=rs; a5*=rs; a6*=rs; a7*=rs;
            m = mn;
#pragma unroll
            for (int i = 0; i < 4; ++i) {
                float p = vd[i] ? __expf(lg[i] - mn) : 0.f;
                s += p;
                float2 v01 = h2f(vv[i].x), v23 = h2f(vv[i].y);
                float2 v45 = h2f(vv[i].z), v67 = h2f(vv[i].w);
                a0 += p * v01.x; a1 += p * v01.y; a2 += p * v23.x; a3 += p * v23.y;
                a4 += p * v45.x; a5 += p * v45.y; a6 += p * v67.x; a7 += p * v67.y;
            }
        }
        float mo = __shfl_xor(m, 32);
        float mt2 = fmaxf(m, mo);
        float myscale = (m == -INFINITY) ? 0.f : __expf(m - mt2);
        float ss = s * myscale;
        float st = ss + __shfl_xor(ss, 32);
        float inv = 1.f / st;
        a0 *= myscale; a0 += __shfl_xor(a0, 32);
        a1 *= myscale; a1 += __shfl_xor(a1, 32);
        a2 *= myscale; a2 += __shfl_xor(a2, 32);
        a3 *= myscale; a3 += __shfl_xor(a3, 32);
        a4 *= myscale; a4 += __shfl_xor(a4, 32);
        a5 *= myscale; a5 += __shfl_xor(a5, 32);
        a6 *= myscale; a6 += __shfl_xor(a6, 32);
        a7 *= myscale; a7 += __shfl_xor(a7, 32);
        a0 *= inv; a1 *= inv; a2 *= inv; a3 *= inv;
        a4 *= inv; a5 *= inv; a6 *= inv; a7 *= inv;
        a0 += __shfl_xor(a0, 8);  a0 += __shfl_xor(a0, 16);
        a1 += __shfl_xor(a1, 8);  a1 += __shfl_xor(a1, 16);
        a2 += __shfl_xor(a2, 8);  a2 += __shfl_xor(a2, 16);
        a3 += __shfl_xor(a3, 8);  a3 += __shfl_xor(a3, 16);
        a4 += __shfl_xor(a4, 8);  a4 += __shfl_xor(a4, 16);
        a5 += __shfl_xor(a5, 8);  a5 += __shfl_xor(a5, 16);
        a6 += __shfl_xor(a6, 8);  a6 += __shfl_xor(a6, 16);
        a7 += __shfl_xor(a7, 8);  a7 += __shfl_xor(a7, 16);
        if (lane < 8) {
            float4 s0 = *reinterpret_cast<const float4*>(&h[(size_t)n * HH + o * 8]);
            float4 s1 = *reinterpret_cast<const float4*>(&h[(size_t)n * HH + o * 8 + 4]);
            float4 r0, r1;
            r0.x = fmaxf(0.25f * a0 + s0.x, 0.f);
            r0.y = fmaxf(0.25f * a1 + s0.y, 0.f);
            r0.z = fmaxf(0.25f * a2 + s0.z, 0.f);
            r0.w = fmaxf(0.25f * a3 + s0.w, 0.f);
            r1.x = fmaxf(0.25f * a4 + s1.x, 0.f);
            r1.y = fmaxf(0.25f * a5 + s1.y, 0.f);
            r1.z = fmaxf(0.25f * a6 + s1.z, 0.f);
            r1.w = fmaxf(0.25f * a7 + s1.w, 0.f);
            *reinterpret_cast<float4*>(&h[(size_t)n * HH + o * 8]) = r0;
            *reinterpret_cast<float4*>(&h[(size_t)n * HH + o * 8 + 4]) = r1;
        }
    }
}

// ---------------------------------------------------------------------------
// Mean pool (batch sorted, run-length accumulate), both branches
// ---------------------------------------------------------------------------
__global__ void k_pool(const float* __restrict__ h0, const int* __restrict__ batA,
                       const int* __restrict__ batB,
                       float* __restrict__ pooled, float* __restrict__ cnt, int N) {
    int br = blockIdx.y;
    const float* h = h0 + (size_t)br * N * HH;
    const int* batch = br ? batB : batA;
    float* pb = pooled + (size_t)br * GG * HH;
    float* cb = cnt + (size_t)br * GG;
    int j = threadIdx.x;
    int n0 = blockIdx.x * 32;
    int n1 = min(n0 + 32, N);
    if (n0 >= N) return;
    float acc = 0.f;
    int c = 0;
    int gcur = batch[n0];
    for (int n = n0; n < n1; ++n) {
        int g = batch[n];
        if (g != gcur) {
            atomicAdd(&pb[gcur * HH + j], acc);
            if (j == 0) atomicAdd(&cb[gcur], (float)c);
            acc = 0.f; c = 0; gcur = g;
        }
        acc += h[(size_t)n * HH + j];
        ++c;
    }
    atomicAdd(&pb[gcur * HH + j], acc);
    if (j == 0) atomicAdd(&cb[gcur], (float)c);
}

// ---------------------------------------------------------------------------
// Head: pool finalize, MHA over seq=2, mean, classifier. Block per graph.
// ---------------------------------------------------------------------------
__global__ void k_head(const float* __restrict__ pooled, const float* __restrict__ cnt,
                       const float* __restrict__ in_w, const float* __restrict__ in_b,
                       const float* __restrict__ out_w, const float* __restrict__ out_b,
                       const float* __restrict__ Wc1, const float* __restrict__ bc1,
                       const float* __restrict__ Wc2, const float* __restrict__ bc2,
                       float* __restrict__ out) {
    int g = blockIdx.x;
    int t = threadIdx.x;
    __shared__ float xs[2][HH];
    __shared__ float qkvs[2][3 * HH];
    __shared__ float sc[2][2][NHEADS];
    __shared__ float os[2][HH];
    __shared__ float xf[HH];
    __shared__ float r1[HH / 2];

    for (int s = 0; s < 2; ++s) {
        float c = fmaxf(cnt[s * GG + g], 1.f);
        xs[s][t] = pooled[(size_t)s * GG * HH + g * HH + t] / c;
    }
    __syncthreads();
    for (int idx = t; idx < 2 * 192; idx += 64) {
        int s = idx / 192, i = idx % 192;
        float a = in_b[i];
#pragma unroll 8
        for (int j = 0; j < HH; ++j) a += xs[s][j] * in_w[i * HH + j];
        qkvs[s][i] = a;
    }
    __syncthreads();
    if (t < 16) {
        int s1 = t >> 3, s2 = (t >> 2) & 1, hh = t & 3;
        float a = 0.f;
#pragma unroll
        for (int d = 0; d < 16; ++d) a += qkvs[s1][hh * 16 + d] * qkvs[s2][HH + hh * 16 + d];
        sc[s1][s2][hh] = a * 0.25f;
    }
    __syncthreads();
    {
        int hh = t >> 4;
        for (int s1 = 0; s1 < 2; ++s1) {
            float a0 = sc[s1][0][hh], a1 = sc[s1][1][hh];
            float mx = fmaxf(a0, a1);
            float e0 = __expf(a0 - mx), e1 = __expf(a1 - mx);
            float inv = 1.f / (e0 + e1);
            os[s1][t] = (e0 * inv) * qkvs[0][2 * HH + t] + (e1 * inv) * qkvs[1][2 * HH + t];
        }
    }
    __syncthreads();
    {
        float acc0 = 0.f, acc1 = 0.f;
#pragma unroll 8
        for (int k2 = 0; k2 < HH; ++k2) {
            float w = out_w[t * HH + k2];
            acc0 += os[0][k2] * w;
            acc1 += os[1][k2] * w;
        }
        xf[t] = 0.5f * (acc0 + acc1) + out_b[t];
    }
    __syncthreads();
    if (t < 32) {
        float a = bc1[t];
#pragma unroll 8
        for (int j = 0; j < HH; ++j) a += xf[j] * Wc1[j * 32 + t];
        r1[t] = fmaxf(a, 0.f);
    }
    __syncthreads();
    if (t < CCLS) {
        float a = bc2[t];
#pragma unroll
        for (int j2 = 0; j2 < 32; ++j2) a += r1[j2] * Wc2[j2 * CCLS + t];
        out[g * CCLS + t] = a;
    }
}

// ---------------------------------------------------------------------------
extern "C" void kernel_launch(void* const* d_in, const int* in_sizes, int n_in,
                              void* d_out, int out_size, void* d_ws, size_t ws_size,
                              hipStream_t stream) {
    const float* x1    = (const float*)d_in[0];
    const float* x2    = (const float*)d_in[1];
    const int*   ei1   = (const int*)d_in[2];
    const int*   ei2   = (const int*)d_in[3];
    const int*   bat1  = (const int*)d_in[4];
    const int*   bat2  = (const int*)d_in[5];
    const float* W_emb = (const float*)d_in[6];
    const float* b_emb = (const float*)d_in[7];
    const float* temb  = (const float*)d_in[8];
    const float* Wq    = (const float*)d_in[9];
    const float* bq    = (const float*)d_in[10];
    const float* Wk    = (const float*)d_in[11];
    const float* bk    = (const float*)d_in[12];
    const float* Wv    = (const float*)d_in[13];
    const float* bv    = (const float*)d_in[14];
    const float* Ws    = (const float*)d_in[15];
    const float* bs    = (const float*)d_in[16];
    const float* miw   = (const float*)d_in[17];
    const float* mib   = (const float*)d_in[18];
    const float* mow   = (const float*)d_in[19];
    const float* mob   = (const float*)d_in[20];
    const float* Wc1   = (const float*)d_in[21];
    const float* bc1   = (const float*)d_in[22];
    const float* Wc2   = (const float*)d_in[23];
    const float* bc2   = (const float*)d_in[24];

    const int N = in_sizes[4];        // 20000
    const int E = in_sizes[2] / 2;    // 320000

    auto al = [](size_t b) { return (b + 255) & ~(size_t)255; };
    auto need = [&](int NBs) -> size_t {
        size_t s = 0;
        s += al((size_t)2 * N * HH * 4);                 // h
        s += al((size_t)NBs * N * 256 * 2);              // qb
        s += al((size_t)NBs * N * 512 * 2);              // kvb
        s += al((size_t)(2 * GG * HH * 4 + 2 * GG * 4 + (size_t)2 * N * 4) + 512); // zero region
        s += al((size_t)2 * (N + 1) * 4);                // indptr
        s += al((size_t)2 * N * 4);                      // cursor
        s += al((size_t)2 * E * 4);                      // srcs
        s += al((size_t)2 * 1024 * 4) * 2;               // btot, btote
        s += al((size_t)3 * 2 * 832 * 64 * 2);           // panel
        s += al((size_t)2 * 64 * 256 * 2);               // panelE
        return s;
    };
    const bool dual = ws_size >= need(2);
    const int NBs = dual ? 2 : 1;

    char* p = (char*)d_ws;
    auto carve = [&](size_t bytes) {
        void* r = (void*)p;
        p += al(bytes);
        return r;
    };
    float*          h      = (float*)carve((size_t)2 * N * HH * 4);
    unsigned short* qb     = (unsigned short*)carve((size_t)NBs * N * 256 * 2);
    unsigned short* kvb    = (unsigned short*)carve((size_t)NBs * N * 512 * 2);
    size_t zbytes = (size_t)2 * GG * HH * 4 + (size_t)2 * GG * 4 + (size_t)2 * N * 4 + 512;
    char*  zbase  = (char*)carve(zbytes);
    float* pooled = (float*)zbase;
    float* cnt    = (float*)(zbase + al((size_t)2 * GG * HH * 4));
    int*   counts = (int*)(zbase + al((size_t)2 * GG * HH * 4) + al((size_t)2 * GG * 4));
    int*            indptr = (int*)carve((size_t)2 * (N + 1) * 4);
    int*            cursor = (int*)carve((size_t)2 * N * 4);
    int*            srcs   = (int*)carve((size_t)2 * E * 4);
    int*            btot   = (int*)carve((size_t)2 * 1024 * 4);
    int*            btote  = (int*)carve((size_t)2 * 1024 * 4);
    unsigned short* panel  = (unsigned short*)carve((size_t)3 * 2 * 832 * 64 * 2);
    unsigned short* panelE = (unsigned short*)carve((size_t)2 * 64 * 256 * 2);

    hipMemsetAsync(zbase, 0, zbytes, stream);

    const int packTot = 3 * 832 * 64 + 64 * 256;
    k_pack<<<(packTot + 255) / 256, 256, 0, stream>>>(Wq, Wk, Wv, Ws, W_emb, panel, panelE);

    const int nb = (N + 1023) / 1024;             // 20
    k_hist<<<dim3((E + 255) / 256, 2), 256, 0, stream>>>(ei1, ei2, E, counts, N);
    k_scan_part<<<dim3(nb, 2), 1024, 0, stream>>>(counts, N, indptr, btot);
    k_scan_mid<<<dim3(1, 2), 1024, 0, stream>>>(nb, btot, btote);
    k_scan_fix<<<dim3(nb, 2), 1024, 0, stream>>>(N, nb, indptr, cursor, btot, btote);
    k_scatter<<<dim3((E + 255) / 256, 2), 256, 0, stream>>>(ei1, ei2, E, cursor, srcs, N);

    const int projGX = (N + 31) / 32;
    const int attnGX = min((N + 3) / 4, 2048);

    for (int pass = 0; pass < (dual ? 1 : 2); ++pass) {
        int brBase = dual ? 0 : pass;
        k_embed_proj<<<dim3(projGX, NBs), 256, 0, stream>>>(
            x1, x2, panelE, b_emb, temb, panel,
            bq, bk, bv, bs, h, qb, kvb, N, brBase);
        k_attn<<<dim3(attnGX, NBs), 256, 0, stream>>>(qb, kvb, indptr, srcs, h, N, E, brBase);
        for (int l = 1; l < LLAY; ++l) {
            k_proj<<<dim3(projGX, NBs), 256, 0, stream>>>(
                h, panel + (size_t)l * 2 * 832 * 64,
                bq + (size_t)l * 256, bk + (size_t)l * 256, bv + (size_t)l * 256, bs + (size_t)l * 64,
                qb, kvb, N, brBase);
            k_attn<<<dim3(attnGX, NBs), 256, 0, stream>>>(qb, kvb, indptr, srcs, h, N, E, brBase);
        }
    }

    k_pool<<<dim3((N + 31) / 32, 2), 64, 0, stream>>>(h, bat1, bat2, pooled, cnt, N);

    k_head<<<GG, 64, 0, stream>>>(pooled, cnt, miw, mib, mow, mob, Wc1, bc1, Wc2, bc2,
                                  (float*)d_out);
}